// Round 5
// baseline (522.253 us; speedup 1.0000x reference)
//
#include <hip/hip_runtime.h>
#include <hip/hip_bf16.h>
#include <math.h>

#define BN_EPS 1e-5f
#define SCAN_CHUNK 1024

typedef __attribute__((ext_vector_type(8)))  short short8v;
typedef __attribute__((ext_vector_type(16))) float f32x16;

__device__ __forceinline__ unsigned short f2bf(float f){
  union { float f; unsigned u; } v; v.f = f;
  unsigned r = v.u + 0x7FFFu + ((v.u >> 16) & 1u);
  return (unsigned short)(r >> 16);
}
__device__ __forceinline__ float bf2f(unsigned short b){
  union { unsigned u; float f; } v; v.u = ((unsigned)b) << 16;
  return v.f;
}

// ---------------- BatchNorm stats: float4 x4-unrolled, LDS reduce ----------------
__global__ __launch_bounds__(256) void bn_stats(const float* __restrict__ x,
                                                float* __restrict__ colsum,
                                                float* __restrict__ colsq, int total4){
  const float4* x4 = (const float4*)x;
  int stride = gridDim.x * blockDim.x;          // multiple of 32 -> c4 fixed per thread
  int idx = blockIdx.x * blockDim.x + threadIdx.x;
  float4 s = make_float4(0.f,0.f,0.f,0.f);
  float4 q = make_float4(0.f,0.f,0.f,0.f);
  for (; idx + 3*stride < total4; idx += 4*stride){
    float4 v0 = x4[idx];
    float4 v1 = x4[idx +   stride];
    float4 v2 = x4[idx + 2*stride];
    float4 v3 = x4[idx + 3*stride];
    s.x += v0.x + v1.x + v2.x + v3.x;
    s.y += v0.y + v1.y + v2.y + v3.y;
    s.z += v0.z + v1.z + v2.z + v3.z;
    s.w += v0.w + v1.w + v2.w + v3.w;
    q.x += v0.x*v0.x + v1.x*v1.x + v2.x*v2.x + v3.x*v3.x;
    q.y += v0.y*v0.y + v1.y*v1.y + v2.y*v2.y + v3.y*v3.y;
    q.z += v0.z*v0.z + v1.z*v1.z + v2.z*v2.z + v3.z*v3.z;
    q.w += v0.w*v0.w + v1.w*v1.w + v2.w*v2.w + v3.w*v3.w;
  }
  for (; idx < total4; idx += stride){
    float4 v = x4[idx];
    s.x += v.x; s.y += v.y; s.z += v.z; s.w += v.w;
    q.x += v.x*v.x; q.y += v.y*v.y; q.z += v.z*v.z; q.w += v.w*v.w;
  }
  __shared__ float4 shs[256], shq[256];
  shs[threadIdx.x] = s; shq[threadIdx.x] = q;
  __syncthreads();
  if (threadIdx.x < 32){
    int c4 = threadIdx.x;
    float4 ts = shs[c4], tq = shq[c4];
    #pragma unroll
    for (int j = 1; j < 8; ++j){
      float4 os = shs[c4 + j*32], oq = shq[c4 + j*32];
      ts.x += os.x; ts.y += os.y; ts.z += os.z; ts.w += os.w;
      tq.x += oq.x; tq.y += oq.y; tq.z += oq.z; tq.w += oq.w;
    }
    atomicAdd(&colsum[c4*4+0], ts.x); atomicAdd(&colsum[c4*4+1], ts.y);
    atomicAdd(&colsum[c4*4+2], ts.z); atomicAdd(&colsum[c4*4+3], ts.w);
    atomicAdd(&colsq[c4*4+0], tq.x);  atomicAdd(&colsq[c4*4+1], tq.y);
    atomicAdd(&colsq[c4*4+2], tq.z);  atomicAdd(&colsq[c4*4+3], tq.w);
  }
}

__global__ void bn_finalize(const float* colsum, const float* colsq, const float* gamma,
                            const float* beta, float* scale, float* shift, int N){
  int c = threadIdx.x;
  float mu  = colsum[c] / (float)N;
  float var = colsq[c] / (float)N - mu*mu;
  float sc  = gamma[c] * rsqrtf(var + BN_EPS);
  scale[c] = sc;
  shift[c] = beta[c] - mu*sc;
}

// ---------------- CSR build ----------------
__global__ void count_deg(const int* __restrict__ dst, int* __restrict__ indeg, int E){
  int e = blockIdx.x*blockDim.x + threadIdx.x;
  if (e < E) atomicAdd(&indeg[dst[e]], 1);
}

__global__ void dinv_k(const int* __restrict__ indeg, float* __restrict__ dinv, int N){
  int v = blockIdx.x*blockDim.x + threadIdx.x;
  if (v < N) dinv[v] = rsqrtf((float)indeg[v] + 1.0f);
}

__global__ __launch_bounds__(256) void scan_part(const int* __restrict__ indeg,
                                                 int* __restrict__ bsum, int N){
  __shared__ int sh[256];
  int base = blockIdx.x * SCAN_CHUNK;
  int s = 0;
  for (int i = threadIdx.x; i < SCAN_CHUNK; i += 256){
    int idx = base + i;
    if (idx < N) s += indeg[idx];
  }
  sh[threadIdx.x] = s; __syncthreads();
  for (int d = 128; d > 0; d >>= 1){
    if (threadIdx.x < d) sh[threadIdx.x] += sh[threadIdx.x + d];
    __syncthreads();
  }
  if (threadIdx.x == 0) bsum[blockIdx.x] = sh[0];
}

__global__ __launch_bounds__(256) void scan_bsum(int* __restrict__ bsum, int nb){
  __shared__ int sh[256];
  int tid = threadIdx.x;
  int v = (tid < nb) ? bsum[tid] : 0;
  sh[tid] = v; __syncthreads();
  for (int d = 1; d < 256; d <<= 1){
    int t = (tid >= d) ? sh[tid-d] : 0;
    __syncthreads();
    sh[tid] += t;
    __syncthreads();
  }
  if (tid < nb) bsum[tid] = sh[tid] - v;
}

__global__ __launch_bounds__(256) void scan_fill(const int* __restrict__ indeg,
                                                 const int* __restrict__ bsum,
                                                 int* __restrict__ rowstart,
                                                 int* __restrict__ cursor, int N){
  __shared__ int sh[256];
  int base = blockIdx.x * SCAN_CHUNK;
  int tid = threadIdx.x;
  int i0 = base + tid*4;
  int v[4]; int s = 0;
  #pragma unroll
  for (int j=0;j<4;j++){
    int idx = i0 + j;
    v[j] = (idx < N) ? indeg[idx] : 0;
    s += v[j];
  }
  sh[tid] = s; __syncthreads();
  for (int d = 1; d < 256; d <<= 1){
    int t = (tid >= d) ? sh[tid-d] : 0;
    __syncthreads();
    sh[tid] += t;
    __syncthreads();
  }
  int off = bsum[blockIdx.x] + sh[tid] - s;
  #pragma unroll
  for (int j=0;j<4;j++){
    int idx = i0 + j;
    if (idx < N){ rowstart[idx] = off; cursor[idx] = off; }
    off += v[j];
  }
  if (blockIdx.x == gridDim.x - 1 && tid == 255) rowstart[N] = off;
}

__global__ void fill_csr(const int* __restrict__ src, const int* __restrict__ dst,
                         const float* __restrict__ dinv, int* __restrict__ cursor,
                         int* __restrict__ csrs, float* __restrict__ csrn, int E){
  int e = blockIdx.x*blockDim.x + threadIdx.x;
  if (e < E){
    int s = src[e], d = dst[e];
    int pos = atomicAdd(&cursor[d], 1);
    csrs[pos] = s;
    csrn[pos] = dinv[s]*dinv[d];
  }
}

__global__ void gbounds(const int* __restrict__ batch, int* __restrict__ gstart, int N, int G){
  int g = blockIdx.x*blockDim.x + threadIdx.x;
  if (g > G) return;
  int lo = 0, hi = N;
  while (lo < hi){ int mid = (lo+hi)>>1; if (batch[mid] < g) lo = mid+1; else hi = mid; }
  gstart[g] = lo;
}

// ---- split W into bf16 hi/lo, transposed layout Wt[l][c][k] ----
__global__ void prep_w(const float* __restrict__ W0, const float* __restrict__ W1,
                       const float* __restrict__ W2, unsigned short* __restrict__ Wh,
                       unsigned short* __restrict__ Wl){
  int idx = blockIdx.x*blockDim.x + threadIdx.x;
  if (idx >= 3*16384) return;
  int l = idx >> 14, r = idx & 16383, c = r >> 7, k = r & 127;
  const float* W = (l==0) ? W0 : (l==1) ? W1 : W2;
  float v = W[k*128 + c];
  unsigned short h = f2bf(v);
  Wh[idx] = h;
  Wl[idx] = f2bf(v - bf2f(h));
}

// ---------------- split-bf16 MFMA GEMM: C[N,128] = A[N,128] @ W ----------------
__global__ __launch_bounds__(256) void gemm_mfma(
    const float* __restrict__ A, const unsigned short* __restrict__ Bh,
    const unsigned short* __restrict__ Bl, const float* __restrict__ scale,
    const float* __restrict__ shift, float* __restrict__ C, int N){
  __shared__ unsigned short Ah[64*128];
  __shared__ unsigned short Al[64*128];
  int tid = threadIdx.x;
  int r0 = blockIdx.x * 64;

  #pragma unroll
  for (int it = 0; it < 8; ++it){
    int idx = tid + it*256;
    int row = idx >> 5;
    int c4  = idx & 31;
    int r = r0 + row;
    float4 av = (r < N) ? *(const float4*)(A + (size_t)r*128 + c4*4)
                        : make_float4(0.f,0.f,0.f,0.f);
    if (scale){
      float4 sc = *(const float4*)(scale + c4*4);
      float4 sh = *(const float4*)(shift + c4*4);
      av.x = av.x*sc.x + sh.x; av.y = av.y*sc.y + sh.y;
      av.z = av.z*sc.z + sh.z; av.w = av.w*sc.w + sh.w;
    }
    float a[4] = {av.x, av.y, av.z, av.w};
    unsigned short hh[4], ll[4];
    #pragma unroll
    for (int j = 0; j < 4; ++j){
      hh[j] = f2bf(a[j]);
      ll[j] = f2bf(a[j] - bf2f(hh[j]));
    }
    int byte0 = (c4*8) ^ ((row & 15) << 4);
    union { unsigned short u[4]; uint2 v; } ph, pl;
    ph.u[0]=hh[0]; ph.u[1]=hh[1]; ph.u[2]=hh[2]; ph.u[3]=hh[3];
    pl.u[0]=ll[0]; pl.u[1]=ll[1]; pl.u[2]=ll[2]; pl.u[3]=ll[3];
    *(uint2*)((char*)Ah + row*256 + byte0) = ph.v;
    *(uint2*)((char*)Al + row*256 + byte0) = pl.v;
  }
  __syncthreads();

  int w = tid >> 6, lane = tid & 63;
  int rt = w & 1;
  int ct = (w >> 1) * 64;
  int lrow = 32*rt + (lane & 31);
  int khalf = lane >> 5;
  int c0 = ct + (lane & 31);

  f32x16 acc0 = {}, acc1 = {};
  const char* AhB = (const char*)Ah + lrow*256;
  const char* AlB = (const char*)Al + lrow*256;
  const unsigned short* bh0 = Bh + (size_t)c0*128 + khalf*8;
  const unsigned short* bl0 = Bl + (size_t)c0*128 + khalf*8;
  int sw = (lrow & 15) << 4;

  #pragma unroll
  for (int s = 0; s < 8; ++s){
    int abyte = (s*32 + khalf*16) ^ sw;
    short8v a_hi = *(const short8v*)(AhB + abyte);
    short8v a_lo = *(const short8v*)(AlB + abyte);
    short8v b_h0 = *(const short8v*)(bh0 + s*16);
    short8v b_l0 = *(const short8v*)(bl0 + s*16);
    short8v b_h1 = *(const short8v*)(bh0 + 32*128 + s*16);
    short8v b_l1 = *(const short8v*)(bl0 + 32*128 + s*16);
    acc0 = __builtin_amdgcn_mfma_f32_32x32x16_bf16(a_hi, b_h0, acc0, 0, 0, 0);
    acc1 = __builtin_amdgcn_mfma_f32_32x32x16_bf16(a_hi, b_h1, acc1, 0, 0, 0);
    acc0 = __builtin_amdgcn_mfma_f32_32x32x16_bf16(a_hi, b_l0, acc0, 0, 0, 0);
    acc1 = __builtin_amdgcn_mfma_f32_32x32x16_bf16(a_hi, b_l1, acc1, 0, 0, 0);
    acc0 = __builtin_amdgcn_mfma_f32_32x32x16_bf16(a_lo, b_h0, acc0, 0, 0, 0);
    acc1 = __builtin_amdgcn_mfma_f32_32x32x16_bf16(a_lo, b_h1, acc1, 0, 0, 0);
  }

  #pragma unroll
  for (int r = 0; r < 16; ++r){
    int row = r0 + 32*rt + (r & 3) + 8*(r >> 2) + 4*khalf;
    if (row < N){
      C[(size_t)row*128 + c0]      = acc0[r];
      C[(size_t)row*128 + c0 + 32] = acc1[r];
    }
  }
}

// ---------------- fused aggregation + bias + squash + attention ----------------
// Half-wave (32 lanes x float4) per node: 2 nodes/wave, 8 nodes/block.
// Edge idx/wt loaded coalesced into lanes, broadcast via 32-wide shuffle;
// 4/2/1 unroll cascade keeps up to 4 gathers in flight per node.
__global__ __launch_bounds__(256) void gather_squash(
    const float* __restrict__ m, const int* __restrict__ rowstart,
    const int* __restrict__ csrs, const float* __restrict__ csrn,
    const float* __restrict__ dinv, const float* __restrict__ bias,
    const float* __restrict__ tar, float* __restrict__ h, float* __restrict__ attn, int N){
  int node = blockIdx.x*8 + (threadIdx.x >> 5);
  if (node >= N) return;
  int lane = threadIdx.x & 31;
  float dv = dinv[node];
  float sn = dv*dv;
  float4 v = ((const float4*)(m + (size_t)node*128))[lane];
  float a0 = v.x*sn, a1 = v.y*sn, a2 = v.z*sn, a3 = v.w*sn;
  int j0 = rowstart[node], j1 = rowstart[node+1];

  for (int base = j0; base < j1; base += 32){
    int cnt = j1 - base; if (cnt > 32) cnt = 32;
    int   sidx = 0; float swt = 0.f;
    if (lane < cnt){ sidx = csrs[base + lane]; swt = csrn[base + lane]; }
    int t = 0;
    for (; t + 4 <= cnt; t += 4){
      int s0 = __shfl(sidx, t, 32),   s1 = __shfl(sidx, t+1, 32);
      int s2 = __shfl(sidx, t+2, 32), s3 = __shfl(sidx, t+3, 32);
      float w0 = __shfl(swt, t, 32),   w1 = __shfl(swt, t+1, 32);
      float w2 = __shfl(swt, t+2, 32), w3 = __shfl(swt, t+3, 32);
      float4 m0 = ((const float4*)(m + (size_t)s0*128))[lane];
      float4 m1 = ((const float4*)(m + (size_t)s1*128))[lane];
      float4 m2 = ((const float4*)(m + (size_t)s2*128))[lane];
      float4 m3 = ((const float4*)(m + (size_t)s3*128))[lane];
      a0 += w0*m0.x + w1*m1.x + w2*m2.x + w3*m3.x;
      a1 += w0*m0.y + w1*m1.y + w2*m2.y + w3*m3.y;
      a2 += w0*m0.z + w1*m1.z + w2*m2.z + w3*m3.z;
      a3 += w0*m0.w + w1*m1.w + w2*m2.w + w3*m3.w;
    }
    if (cnt - t >= 2){
      int s0 = __shfl(sidx, t, 32), s1 = __shfl(sidx, t+1, 32);
      float w0 = __shfl(swt, t, 32), w1 = __shfl(swt, t+1, 32);
      float4 m0 = ((const float4*)(m + (size_t)s0*128))[lane];
      float4 m1 = ((const float4*)(m + (size_t)s1*128))[lane];
      a0 += w0*m0.x + w1*m1.x;
      a1 += w0*m0.y + w1*m1.y;
      a2 += w0*m0.z + w1*m1.z;
      a3 += w0*m0.w + w1*m1.w;
      t += 2;
    }
    if (t < cnt){
      int s0 = __shfl(sidx, t, 32);
      float w0 = __shfl(swt, t, 32);
      float4 m0 = ((const float4*)(m + (size_t)s0*128))[lane];
      a0 += w0*m0.x; a1 += w0*m0.y; a2 += w0*m0.z; a3 += w0*m0.w;
    }
  }

  float4 bv = ((const float4*)bias)[lane];
  a0 += bv.x; a1 += bv.y; a2 += bv.z; a3 += bv.w;
  float n2 = a0*a0 + a1*a1 + a2*a2 + a3*a3;
  #pragma unroll
  for (int o = 16; o > 0; o >>= 1) n2 += __shfl_xor(n2, o);
  float sc = (n2/(1.f+n2)) * rsqrtf(n2 + 1e-12f);
  float h0 = a0*sc, h1 = a1*sc, h2 = a2*sc, h3 = a3*sc;
  ((float4*)(h + (size_t)node*128))[lane] = make_float4(h0, h1, h2, h3);
  float4 tv = ((const float4*)tar)[lane];
  float at = h0*tv.x + h1*tv.y + h2*tv.z + h3*tv.w;
  #pragma unroll
  for (int o = 16; o > 0; o >>= 1) at += __shfl_xor(at, o);
  if (lane == 0) attn[node] = at;
}

// ---------------- per-graph readout (wsum / mean / max), accumulated ----------------
__global__ __launch_bounds__(1024) void readout(const float* __restrict__ h,
                                                const float* __restrict__ attn,
                                                const int* __restrict__ gstart,
                                                float* __restrict__ grep){
  int g = blockIdx.x;
  int t   = threadIdx.x & 63;   // float2 feature pair
  int grp = threadIdx.x >> 6;   // 0..15 node groups
  int a = gstart[g], b = gstart[g+1];
  float wsx = 0.f, wsy = 0.f, smx_ = 0.f, smy_ = 0.f;
  float mxx = -INFINITY, mxy = -INFINITY;
  for (int n = a + grp; n < b; n += 16){
    float2 v  = ((const float2*)(h + (size_t)n*128))[t];
    float at = attn[n];
    wsx += at*v.x; wsy += at*v.y;
    smx_ += v.x;  smy_ += v.y;
    mxx = fmaxf(mxx, v.x); mxy = fmaxf(mxy, v.y);
  }
  __shared__ float2 sws[16][64], ssm[16][64], smx[16][64];
  sws[grp][t] = make_float2(wsx, wsy);
  ssm[grp][t] = make_float2(smx_, smy_);
  smx[grp][t] = make_float2(mxx, mxy);
  __syncthreads();
  if (grp == 0){
    #pragma unroll
    for (int j = 1; j < 16; ++j){
      float2 ow = sws[j][t], os = ssm[j][t], om = smx[j][t];
      wsx += ow.x; wsy += ow.y;
      smx_ += os.x; smy_ += os.y;
      mxx = fmaxf(mxx, om.x); mxy = fmaxf(mxy, om.y);
    }
    int cnt = b - a;
    float inv = 1.f / fmaxf((float)cnt, 1.f);
    if (cnt == 0){ mxx = 0.f; mxy = 0.f; }
    grep[(size_t)g*384 + t*2]           += wsx;
    grep[(size_t)g*384 + t*2 + 1]       += wsy;
    grep[(size_t)g*384 + 128 + t*2]     += smx_*inv;
    grep[(size_t)g*384 + 128 + t*2 + 1] += smy_*inv;
    grep[(size_t)g*384 + 256 + t*2]     += mxx;
    grep[(size_t)g*384 + 256 + t*2 + 1] += mxy;
  }
}

// ---------------- classifier head + log_softmax ----------------
__global__ __launch_bounds__(128) void classify(const float* __restrict__ grep,
                                                const float* __restrict__ w1, const float* __restrict__ b1,
                                                const float* __restrict__ w2, const float* __restrict__ b2,
                                                float* __restrict__ out){
  int g = blockIdx.x, t = threadIdx.x;
  __shared__ float gr[384];
  for (int i = t; i < 384; i += 128) gr[i] = grep[(size_t)g*384 + i];
  __syncthreads();
  float z = b1[t];
  for (int k = 0; k < 384; ++k) z += gr[k]*w1[k*128 + t];
  z = fmaxf(z, 0.f);
  float c0 = z*w2[t*2 + 0], c1 = z*w2[t*2 + 1];
  #pragma unroll
  for (int o = 32; o > 0; o >>= 1){ c0 += __shfl_xor(c0, o); c1 += __shfl_xor(c1, o); }
  __shared__ float r0s[2], r1s[2];
  if ((t & 63) == 0){ r0s[t>>6] = c0; r1s[t>>6] = c1; }
  __syncthreads();
  if (t == 0){
    float z0 = r0s[0] + r0s[1] + b2[0];
    float z1 = r1s[0] + r1s[1] + b2[1];
    float mm = fmaxf(z0, z1);
    float lse = mm + logf(expf(z0-mm) + expf(z1-mm));
    out[g*2 + 0] = z0 - lse;
    out[g*2 + 1] = z1 - lse;
  }
}

extern "C" void kernel_launch(void* const* d_in, const int* in_sizes, int n_in,
                              void* d_out, int out_size, void* d_ws, size_t ws_size,
                              hipStream_t stream) {
  const float* x     = (const float*)d_in[0];
  const int*   ei    = (const int*)d_in[1];
  const int*   batch = (const int*)d_in[2];
  const float* gamma = (const float*)d_in[3];
  const float* beta  = (const float*)d_in[4];
  const float* W0    = (const float*)d_in[5];
  const float* b0    = (const float*)d_in[6];
  const float* W1    = (const float*)d_in[7];
  const float* b1    = (const float*)d_in[8];
  const float* W2    = (const float*)d_in[9];
  const float* b2    = (const float*)d_in[10];
  const float* tar   = (const float*)d_in[11];
  const float* l1w   = (const float*)d_in[12];
  const float* l1b   = (const float*)d_in[13];
  const float* l2w   = (const float*)d_in[14];
  const float* l2b   = (const float*)d_in[15];
  float* out = (float*)d_out;

  int N = in_sizes[0] / 128;
  int E = in_sizes[1] / 2;
  int G = out_size / 2;
  const int* srcp = ei;
  const int* dstp = ei + E;

  char* wsb = (char*)d_ws;
  size_t off = 0;
  auto alloc = [&](size_t bytes)->char*{
    char* p = wsb + off; off += (bytes + 255) & ~(size_t)255; return p;
  };
  float* h       = (float*)alloc((size_t)N*128*4);
  float* m       = (float*)alloc((size_t)N*128*4);
  float* attn    = (float*)alloc((size_t)N*4);
  float* dinv    = (float*)alloc((size_t)N*4);
  int*   indeg   = (int*)  alloc((size_t)N*4);
  int*   rowst   = (int*)  alloc((size_t)(N+1)*4);
  int*   cursor  = (int*)  alloc((size_t)N*4);
  int*   csrs    = (int*)  alloc((size_t)E*4);
  float* csrn    = (float*)alloc((size_t)E*4);
  int*   gstart  = (int*)  alloc((size_t)(G+1)*4);
  float* grep    = (float*)alloc((size_t)G*384*4);
  float* stats   = (float*)alloc(4*128*4);
  unsigned short* Wh = (unsigned short*)alloc(3*16384*2);
  unsigned short* Wl = (unsigned short*)alloc(3*16384*2);
  int*   bsum    = (int*)  alloc(256*4);
  (void)ws_size;

  float* colsum = stats;
  float* colsq  = stats + 128;
  float* scale  = stats + 256;
  float* shift  = stats + 384;

  hipMemsetAsync(colsum, 0, 2*128*4, stream);
  hipMemsetAsync(indeg, 0, (size_t)N*4, stream);
  hipMemsetAsync(grep, 0, (size_t)G*384*4, stream);

  bn_stats<<<1024, 256, 0, stream>>>(x, colsum, colsq, N*32);
  bn_finalize<<<1, 128, 0, stream>>>(colsum, colsq, gamma, beta, scale, shift, N);

  int nb = (N + SCAN_CHUNK - 1) / SCAN_CHUNK;
  count_deg<<<(E+255)/256, 256, 0, stream>>>(dstp, indeg, E);
  dinv_k<<<(N+255)/256, 256, 0, stream>>>(indeg, dinv, N);
  scan_part<<<nb, 256, 0, stream>>>(indeg, bsum, N);
  scan_bsum<<<1, 256, 0, stream>>>(bsum, nb);
  scan_fill<<<nb, 256, 0, stream>>>(indeg, bsum, rowst, cursor, N);
  fill_csr<<<(E+255)/256, 256, 0, stream>>>(srcp, dstp, dinv, cursor, csrs, csrn, E);
  gbounds<<<(G+1+255)/256, 256, 0, stream>>>(batch, gstart, N, G);
  prep_w<<<(3*16384+255)/256, 256, 0, stream>>>(W0, W1, W2, Wh, Wl);

  const float* bs[3] = {b0, b1, b2};
  for (int l = 0; l < 3; ++l){
    const float* src_mat = (l == 0) ? x : h;
    const float* sc = (l == 0) ? scale : nullptr;
    const float* sh = (l == 0) ? shift : nullptr;
    gemm_mfma<<<(N+63)/64, 256, 0, stream>>>(src_mat, Wh + l*16384, Wl + l*16384, sc, sh, m, N);
    gather_squash<<<(N+7)/8, 256, 0, stream>>>(m, rowst, csrs, csrn, dinv, bs[l], tar + l*128, h, attn, N);
    readout<<<G, 1024, 0, stream>>>(h, attn, gstart, grep);
  }
  classify<<<G, 128, 0, stream>>>(grep, l1w, l1b, l2w, l2b, out);
}

// Round 6
// 436.975 us; speedup vs baseline: 1.1952x; 1.1952x over previous
//
#include <hip/hip_runtime.h>
#include <hip/hip_bf16.h>
#include <math.h>

#define BN_EPS 1e-5f
#define SCAN_CHUNK 1024
#define BN_BLOCKS 512

typedef __attribute__((ext_vector_type(8)))  short short8v;
typedef __attribute__((ext_vector_type(16))) float f32x16;

__device__ __forceinline__ unsigned short f2bf(float f){
  union { float f; unsigned u; } v; v.f = f;
  unsigned r = v.u + 0x7FFFu + ((v.u >> 16) & 1u);
  return (unsigned short)(r >> 16);
}
__device__ __forceinline__ float bf2f(unsigned short b){
  union { unsigned u; float f; } v; v.u = ((unsigned)b) << 16;
  return v.f;
}

// ---------------- BatchNorm stats, stage 1: per-block partials (NO atomics) ----------------
// part[b][0..127] = column sums, part[b][128..255] = column sums of squares
__global__ __launch_bounds__(256) void bn_part(const float* __restrict__ x,
                                               float* __restrict__ part, int total4){
  const float4* x4 = (const float4*)x;
  int stride = gridDim.x * blockDim.x;          // multiple of 32 -> c4 fixed per thread
  float4 s = make_float4(0.f,0.f,0.f,0.f);
  float4 q = make_float4(0.f,0.f,0.f,0.f);
  for (int idx = blockIdx.x*blockDim.x + threadIdx.x; idx < total4; idx += stride){
    float4 v = x4[idx];
    s.x += v.x; s.y += v.y; s.z += v.z; s.w += v.w;
    q.x += v.x*v.x; q.y += v.y*v.y; q.z += v.z*v.z; q.w += v.w*v.w;
  }
  __shared__ float4 shs[256], shq[256];
  shs[threadIdx.x] = s; shq[threadIdx.x] = q;
  __syncthreads();
  if (threadIdx.x < 32){
    int c4 = threadIdx.x;
    float4 ts = shs[c4], tq = shq[c4];
    #pragma unroll
    for (int j = 1; j < 8; ++j){
      float4 os = shs[c4 + j*32], oq = shq[c4 + j*32];
      ts.x += os.x; ts.y += os.y; ts.z += os.z; ts.w += os.w;
      tq.x += oq.x; tq.y += oq.y; tq.z += oq.z; tq.w += oq.w;
    }
    float* pb = part + (size_t)blockIdx.x * 256;
    *(float4*)(pb + c4*4)       = ts;
    *(float4*)(pb + 128 + c4*4) = tq;
  }
}

// ---------------- stage 2: reduce partials + finalize scale/shift ----------------
__global__ __launch_bounds__(256) void bn_reduce(const float* __restrict__ part,
                                                 const float* __restrict__ gamma,
                                                 const float* __restrict__ beta,
                                                 float* __restrict__ scale,
                                                 float* __restrict__ shift, int N){
  int t = threadIdx.x;   // t<128: column sums; t>=128: column sq-sums
  float a0=0.f,a1=0.f,a2=0.f,a3=0.f,a4=0.f,a5=0.f,a6=0.f,a7=0.f;
  for (int b = 0; b < BN_BLOCKS; b += 8){
    a0 += part[(size_t)(b+0)*256 + t];
    a1 += part[(size_t)(b+1)*256 + t];
    a2 += part[(size_t)(b+2)*256 + t];
    a3 += part[(size_t)(b+3)*256 + t];
    a4 += part[(size_t)(b+4)*256 + t];
    a5 += part[(size_t)(b+5)*256 + t];
    a6 += part[(size_t)(b+6)*256 + t];
    a7 += part[(size_t)(b+7)*256 + t];
  }
  float acc = ((a0+a1)+(a2+a3)) + ((a4+a5)+(a6+a7));
  __shared__ float sh[256];
  sh[t] = acc;
  __syncthreads();
  if (t < 128){
    float mu  = sh[t] / (float)N;
    float var = sh[t+128] / (float)N - mu*mu;
    float sc  = gamma[t] * rsqrtf(var + BN_EPS);
    scale[t] = sc;
    shift[t] = beta[t] - mu*sc;
  }
}

// ---------------- CSR build ----------------
__global__ void count_deg(const int* __restrict__ dst, int* __restrict__ indeg, int E){
  int e = blockIdx.x*blockDim.x + threadIdx.x;
  if (e < E) atomicAdd(&indeg[dst[e]], 1);
}

__global__ void dinv_k(const int* __restrict__ indeg, float* __restrict__ dinv, int N){
  int v = blockIdx.x*blockDim.x + threadIdx.x;
  if (v < N) dinv[v] = rsqrtf((float)indeg[v] + 1.0f);
}

__global__ __launch_bounds__(256) void scan_part(const int* __restrict__ indeg,
                                                 int* __restrict__ bsum, int N){
  __shared__ int sh[256];
  int base = blockIdx.x * SCAN_CHUNK;
  int s = 0;
  for (int i = threadIdx.x; i < SCAN_CHUNK; i += 256){
    int idx = base + i;
    if (idx < N) s += indeg[idx];
  }
  sh[threadIdx.x] = s; __syncthreads();
  for (int d = 128; d > 0; d >>= 1){
    if (threadIdx.x < d) sh[threadIdx.x] += sh[threadIdx.x + d];
    __syncthreads();
  }
  if (threadIdx.x == 0) bsum[blockIdx.x] = sh[0];
}

__global__ __launch_bounds__(256) void scan_bsum(int* __restrict__ bsum, int nb){
  __shared__ int sh[256];
  int tid = threadIdx.x;
  int v = (tid < nb) ? bsum[tid] : 0;
  sh[tid] = v; __syncthreads();
  for (int d = 1; d < 256; d <<= 1){
    int t = (tid >= d) ? sh[tid-d] : 0;
    __syncthreads();
    sh[tid] += t;
    __syncthreads();
  }
  if (tid < nb) bsum[tid] = sh[tid] - v;
}

__global__ __launch_bounds__(256) void scan_fill(const int* __restrict__ indeg,
                                                 const int* __restrict__ bsum,
                                                 int* __restrict__ rowstart,
                                                 int* __restrict__ cursor, int N){
  __shared__ int sh[256];
  int base = blockIdx.x * SCAN_CHUNK;
  int tid = threadIdx.x;
  int i0 = base + tid*4;
  int v[4]; int s = 0;
  #pragma unroll
  for (int j=0;j<4;j++){
    int idx = i0 + j;
    v[j] = (idx < N) ? indeg[idx] : 0;
    s += v[j];
  }
  sh[tid] = s; __syncthreads();
  for (int d = 1; d < 256; d <<= 1){
    int t = (tid >= d) ? sh[tid-d] : 0;
    __syncthreads();
    sh[tid] += t;
    __syncthreads();
  }
  int off = bsum[blockIdx.x] + sh[tid] - s;
  #pragma unroll
  for (int j=0;j<4;j++){
    int idx = i0 + j;
    if (idx < N){ rowstart[idx] = off; cursor[idx] = off; }
    off += v[j];
  }
  if (blockIdx.x == gridDim.x - 1 && tid == 255) rowstart[N] = off;
}

__global__ void fill_csr(const int* __restrict__ src, const int* __restrict__ dst,
                         const float* __restrict__ dinv, int* __restrict__ cursor,
                         int* __restrict__ csrs, float* __restrict__ csrn, int E){
  int e = blockIdx.x*blockDim.x + threadIdx.x;
  if (e < E){
    int s = src[e], d = dst[e];
    int pos = atomicAdd(&cursor[d], 1);
    csrs[pos] = s;
    csrn[pos] = dinv[s]*dinv[d];
  }
}

__global__ void gbounds(const int* __restrict__ batch, int* __restrict__ gstart, int N, int G){
  int g = blockIdx.x*blockDim.x + threadIdx.x;
  if (g > G) return;
  int lo = 0, hi = N;
  while (lo < hi){ int mid = (lo+hi)>>1; if (batch[mid] < g) lo = mid+1; else hi = mid; }
  gstart[g] = lo;
}

// ---- split W into bf16 hi/lo, transposed layout Wt[l][c][k] ----
__global__ void prep_w(const float* __restrict__ W0, const float* __restrict__ W1,
                       const float* __restrict__ W2, unsigned short* __restrict__ Wh,
                       unsigned short* __restrict__ Wl){
  int idx = blockIdx.x*blockDim.x + threadIdx.x;
  if (idx >= 3*16384) return;
  int l = idx >> 14, r = idx & 16383, c = r >> 7, k = r & 127;
  const float* W = (l==0) ? W0 : (l==1) ? W1 : W2;
  float v = W[k*128 + c];
  unsigned short h = f2bf(v);
  Wh[idx] = h;
  Wl[idx] = f2bf(v - bf2f(h));
}

// ---------------- split-bf16 MFMA GEMM: C[N,128] = A[N,128] @ W ----------------
__global__ __launch_bounds__(256) void gemm_mfma(
    const float* __restrict__ A, const unsigned short* __restrict__ Bh,
    const unsigned short* __restrict__ Bl, const float* __restrict__ scale,
    const float* __restrict__ shift, float* __restrict__ C, int N){
  __shared__ unsigned short Ah[64*128];
  __shared__ unsigned short Al[64*128];
  int tid = threadIdx.x;
  int r0 = blockIdx.x * 64;

  #pragma unroll
  for (int it = 0; it < 8; ++it){
    int idx = tid + it*256;
    int row = idx >> 5;
    int c4  = idx & 31;
    int r = r0 + row;
    float4 av = (r < N) ? *(const float4*)(A + (size_t)r*128 + c4*4)
                        : make_float4(0.f,0.f,0.f,0.f);
    if (scale){
      float4 sc = *(const float4*)(scale + c4*4);
      float4 sh = *(const float4*)(shift + c4*4);
      av.x = av.x*sc.x + sh.x; av.y = av.y*sc.y + sh.y;
      av.z = av.z*sc.z + sh.z; av.w = av.w*sc.w + sh.w;
    }
    float a[4] = {av.x, av.y, av.z, av.w};
    unsigned short hh[4], ll[4];
    #pragma unroll
    for (int j = 0; j < 4; ++j){
      hh[j] = f2bf(a[j]);
      ll[j] = f2bf(a[j] - bf2f(hh[j]));
    }
    int byte0 = (c4*8) ^ ((row & 15) << 4);
    union { unsigned short u[4]; uint2 v; } ph, pl;
    ph.u[0]=hh[0]; ph.u[1]=hh[1]; ph.u[2]=hh[2]; ph.u[3]=hh[3];
    pl.u[0]=ll[0]; pl.u[1]=ll[1]; pl.u[2]=ll[2]; pl.u[3]=ll[3];
    *(uint2*)((char*)Ah + row*256 + byte0) = ph.v;
    *(uint2*)((char*)Al + row*256 + byte0) = pl.v;
  }
  __syncthreads();

  int w = tid >> 6, lane = tid & 63;
  int rt = w & 1;
  int ct = (w >> 1) * 64;
  int lrow = 32*rt + (lane & 31);
  int khalf = lane >> 5;
  int c0 = ct + (lane & 31);

  f32x16 acc0 = {}, acc1 = {};
  const char* AhB = (const char*)Ah + lrow*256;
  const char* AlB = (const char*)Al + lrow*256;
  const unsigned short* bh0 = Bh + (size_t)c0*128 + khalf*8;
  const unsigned short* bl0 = Bl + (size_t)c0*128 + khalf*8;
  int sw = (lrow & 15) << 4;

  #pragma unroll
  for (int s = 0; s < 8; ++s){
    int abyte = (s*32 + khalf*16) ^ sw;
    short8v a_hi = *(const short8v*)(AhB + abyte);
    short8v a_lo = *(const short8v*)(AlB + abyte);
    short8v b_h0 = *(const short8v*)(bh0 + s*16);
    short8v b_l0 = *(const short8v*)(bl0 + s*16);
    short8v b_h1 = *(const short8v*)(bh0 + 32*128 + s*16);
    short8v b_l1 = *(const short8v*)(bl0 + 32*128 + s*16);
    acc0 = __builtin_amdgcn_mfma_f32_32x32x16_bf16(a_hi, b_h0, acc0, 0, 0, 0);
    acc1 = __builtin_amdgcn_mfma_f32_32x32x16_bf16(a_hi, b_h1, acc1, 0, 0, 0);
    acc0 = __builtin_amdgcn_mfma_f32_32x32x16_bf16(a_hi, b_l0, acc0, 0, 0, 0);
    acc1 = __builtin_amdgcn_mfma_f32_32x32x16_bf16(a_hi, b_l1, acc1, 0, 0, 0);
    acc0 = __builtin_amdgcn_mfma_f32_32x32x16_bf16(a_lo, b_h0, acc0, 0, 0, 0);
    acc1 = __builtin_amdgcn_mfma_f32_32x32x16_bf16(a_lo, b_h1, acc1, 0, 0, 0);
  }

  #pragma unroll
  for (int r = 0; r < 16; ++r){
    int row = r0 + 32*rt + (r & 3) + 8*(r >> 2) + 4*khalf;
    if (row < N){
      C[(size_t)row*128 + c0]      = acc0[r];
      C[(size_t)row*128 + c0 + 32] = acc1[r];
    }
  }
}

// ---------------- fused aggregation + bias + squash + attention ----------------
__global__ __launch_bounds__(256) void gather_squash(
    const float* __restrict__ m, const int* __restrict__ rowstart,
    const int* __restrict__ csrs, const float* __restrict__ csrn,
    const float* __restrict__ dinv, const float* __restrict__ bias,
    const float* __restrict__ tar, float* __restrict__ h, float* __restrict__ attn, int N){
  int node = blockIdx.x*8 + (threadIdx.x >> 5);
  if (node >= N) return;
  int lane = threadIdx.x & 31;
  float dv = dinv[node];
  float sn = dv*dv;
  float4 v = ((const float4*)(m + (size_t)node*128))[lane];
  float a0 = v.x*sn, a1 = v.y*sn, a2 = v.z*sn, a3 = v.w*sn;
  int j0 = rowstart[node], j1 = rowstart[node+1];

  for (int base = j0; base < j1; base += 32){
    int cnt = j1 - base; if (cnt > 32) cnt = 32;
    int   sidx = 0; float swt = 0.f;
    if (lane < cnt){ sidx = csrs[base + lane]; swt = csrn[base + lane]; }
    int t = 0;
    for (; t + 4 <= cnt; t += 4){
      int s0 = __shfl(sidx, t, 32),   s1 = __shfl(sidx, t+1, 32);
      int s2 = __shfl(sidx, t+2, 32), s3 = __shfl(sidx, t+3, 32);
      float w0 = __shfl(swt, t, 32),   w1 = __shfl(swt, t+1, 32);
      float w2 = __shfl(swt, t+2, 32), w3 = __shfl(swt, t+3, 32);
      float4 m0 = ((const float4*)(m + (size_t)s0*128))[lane];
      float4 m1 = ((const float4*)(m + (size_t)s1*128))[lane];
      float4 m2 = ((const float4*)(m + (size_t)s2*128))[lane];
      float4 m3 = ((const float4*)(m + (size_t)s3*128))[lane];
      a0 += w0*m0.x + w1*m1.x + w2*m2.x + w3*m3.x;
      a1 += w0*m0.y + w1*m1.y + w2*m2.y + w3*m3.y;
      a2 += w0*m0.z + w1*m1.z + w2*m2.z + w3*m3.z;
      a3 += w0*m0.w + w1*m1.w + w2*m2.w + w3*m3.w;
    }
    if (cnt - t >= 2){
      int s0 = __shfl(sidx, t, 32), s1 = __shfl(sidx, t+1, 32);
      float w0 = __shfl(swt, t, 32), w1 = __shfl(swt, t+1, 32);
      float4 m0 = ((const float4*)(m + (size_t)s0*128))[lane];
      float4 m1 = ((const float4*)(m + (size_t)s1*128))[lane];
      a0 += w0*m0.x + w1*m1.x;
      a1 += w0*m0.y + w1*m1.y;
      a2 += w0*m0.z + w1*m1.z;
      a3 += w0*m0.w + w1*m1.w;
      t += 2;
    }
    if (t < cnt){
      int s0 = __shfl(sidx, t, 32);
      float w0 = __shfl(swt, t, 32);
      float4 m0 = ((const float4*)(m + (size_t)s0*128))[lane];
      a0 += w0*m0.x; a1 += w0*m0.y; a2 += w0*m0.z; a3 += w0*m0.w;
    }
  }

  float4 bv = ((const float4*)bias)[lane];
  a0 += bv.x; a1 += bv.y; a2 += bv.z; a3 += bv.w;
  float n2 = a0*a0 + a1*a1 + a2*a2 + a3*a3;
  #pragma unroll
  for (int o = 16; o > 0; o >>= 1) n2 += __shfl_xor(n2, o);
  float sc = (n2/(1.f+n2)) * rsqrtf(n2 + 1e-12f);
  float h0 = a0*sc, h1 = a1*sc, h2 = a2*sc, h3 = a3*sc;
  ((float4*)(h + (size_t)node*128))[lane] = make_float4(h0, h1, h2, h3);
  float4 tv = ((const float4*)tar)[lane];
  float at = h0*tv.x + h1*tv.y + h2*tv.z + h3*tv.w;
  #pragma unroll
  for (int o = 16; o > 0; o >>= 1) at += __shfl_xor(at, o);
  if (lane == 0) attn[node] = at;
}

// ---------------- per-graph readout (wsum / mean / max), accumulated ----------------
__global__ __launch_bounds__(1024) void readout(const float* __restrict__ h,
                                                const float* __restrict__ attn,
                                                const int* __restrict__ gstart,
                                                float* __restrict__ grep){
  int g = blockIdx.x;
  int t   = threadIdx.x & 63;
  int grp = threadIdx.x >> 6;
  int a = gstart[g], b = gstart[g+1];
  float wsx = 0.f, wsy = 0.f, smx_ = 0.f, smy_ = 0.f;
  float mxx = -INFINITY, mxy = -INFINITY;
  for (int n = a + grp; n < b; n += 16){
    float2 v  = ((const float2*)(h + (size_t)n*128))[t];
    float at = attn[n];
    wsx += at*v.x; wsy += at*v.y;
    smx_ += v.x;  smy_ += v.y;
    mxx = fmaxf(mxx, v.x); mxy = fmaxf(mxy, v.y);
  }
  __shared__ float2 sws[16][64], ssm[16][64], smx[16][64];
  sws[grp][t] = make_float2(wsx, wsy);
  ssm[grp][t] = make_float2(smx_, smy_);
  smx[grp][t] = make_float2(mxx, mxy);
  __syncthreads();
  if (grp == 0){
    #pragma unroll
    for (int j = 1; j < 16; ++j){
      float2 ow = sws[j][t], os = ssm[j][t], om = smx[j][t];
      wsx += ow.x; wsy += ow.y;
      smx_ += os.x; smy_ += os.y;
      mxx = fmaxf(mxx, om.x); mxy = fmaxf(mxy, om.y);
    }
    int cnt = b - a;
    float inv = 1.f / fmaxf((float)cnt, 1.f);
    if (cnt == 0){ mxx = 0.f; mxy = 0.f; }
    grep[(size_t)g*384 + t*2]           += wsx;
    grep[(size_t)g*384 + t*2 + 1]       += wsy;
    grep[(size_t)g*384 + 128 + t*2]     += smx_*inv;
    grep[(size_t)g*384 + 128 + t*2 + 1] += smy_*inv;
    grep[(size_t)g*384 + 256 + t*2]     += mxx;
    grep[(size_t)g*384 + 256 + t*2 + 1] += mxy;
  }
}

// ---------------- classifier head + log_softmax ----------------
__global__ __launch_bounds__(128) void classify(const float* __restrict__ grep,
                                                const float* __restrict__ w1, const float* __restrict__ b1,
                                                const float* __restrict__ w2, const float* __restrict__ b2,
                                                float* __restrict__ out){
  int g = blockIdx.x, t = threadIdx.x;
  __shared__ float gr[384];
  for (int i = t; i < 384; i += 128) gr[i] = grep[(size_t)g*384 + i];
  __syncthreads();
  float z = b1[t];
  for (int k = 0; k < 384; ++k) z += gr[k]*w1[k*128 + t];
  z = fmaxf(z, 0.f);
  float c0 = z*w2[t*2 + 0], c1 = z*w2[t*2 + 1];
  #pragma unroll
  for (int o = 32; o > 0; o >>= 1){ c0 += __shfl_xor(c0, o); c1 += __shfl_xor(c1, o); }
  __shared__ float r0s[2], r1s[2];
  if ((t & 63) == 0){ r0s[t>>6] = c0; r1s[t>>6] = c1; }
  __syncthreads();
  if (t == 0){
    float z0 = r0s[0] + r0s[1] + b2[0];
    float z1 = r1s[0] + r1s[1] + b2[1];
    float mm = fmaxf(z0, z1);
    float lse = mm + logf(expf(z0-mm) + expf(z1-mm));
    out[g*2 + 0] = z0 - lse;
    out[g*2 + 1] = z1 - lse;
  }
}

extern "C" void kernel_launch(void* const* d_in, const int* in_sizes, int n_in,
                              void* d_out, int out_size, void* d_ws, size_t ws_size,
                              hipStream_t stream) {
  const float* x     = (const float*)d_in[0];
  const int*   ei    = (const int*)d_in[1];
  const int*   batch = (const int*)d_in[2];
  const float* gamma = (const float*)d_in[3];
  const float* beta  = (const float*)d_in[4];
  const float* W0    = (const float*)d_in[5];
  const float* b0    = (const float*)d_in[6];
  const float* W1    = (const float*)d_in[7];
  const float* b1    = (const float*)d_in[8];
  const float* W2    = (const float*)d_in[9];
  const float* b2    = (const float*)d_in[10];
  const float* tar   = (const float*)d_in[11];
  const float* l1w   = (const float*)d_in[12];
  const float* l1b   = (const float*)d_in[13];
  const float* l2w   = (const float*)d_in[14];
  const float* l2b   = (const float*)d_in[15];
  float* out = (float*)d_out;

  int N = in_sizes[0] / 128;
  int E = in_sizes[1] / 2;
  int G = out_size / 2;
  const int* srcp = ei;
  const int* dstp = ei + E;

  char* wsb = (char*)d_ws;
  size_t off = 0;
  auto alloc = [&](size_t bytes)->char*{
    char* p = wsb + off; off += (bytes + 255) & ~(size_t)255; return p;
  };
  float* h       = (float*)alloc((size_t)N*128*4);
  float* m       = (float*)alloc((size_t)N*128*4);
  float* attn    = (float*)alloc((size_t)N*4);
  float* dinv    = (float*)alloc((size_t)N*4);
  int*   indeg   = (int*)  alloc((size_t)N*4);
  int*   rowst   = (int*)  alloc((size_t)(N+1)*4);
  int*   cursor  = (int*)  alloc((size_t)N*4);
  int*   csrs    = (int*)  alloc((size_t)E*4);
  float* csrn    = (float*)alloc((size_t)E*4);
  int*   gstart  = (int*)  alloc((size_t)(G+1)*4);
  float* grep    = (float*)alloc((size_t)G*384*4);
  float* stats   = (float*)alloc(2*128*4);
  float* part    = (float*)alloc((size_t)BN_BLOCKS*256*4);
  unsigned short* Wh = (unsigned short*)alloc(3*16384*2);
  unsigned short* Wl = (unsigned short*)alloc(3*16384*2);
  int*   bsum    = (int*)  alloc(256*4);
  (void)ws_size;

  float* scale  = stats;
  float* shift  = stats + 128;

  hipMemsetAsync(indeg, 0, (size_t)N*4, stream);
  hipMemsetAsync(grep, 0, (size_t)G*384*4, stream);

  // --- CSR build first (independent of BN; absorbs any first-kernel cold-start) ---
  int nb = (N + SCAN_CHUNK - 1) / SCAN_CHUNK;
  count_deg<<<(E+255)/256, 256, 0, stream>>>(dstp, indeg, E);
  dinv_k<<<(N+255)/256, 256, 0, stream>>>(indeg, dinv, N);
  scan_part<<<nb, 256, 0, stream>>>(indeg, bsum, N);
  scan_bsum<<<1, 256, 0, stream>>>(bsum, nb);
  scan_fill<<<nb, 256, 0, stream>>>(indeg, bsum, rowst, cursor, N);
  fill_csr<<<(E+255)/256, 256, 0, stream>>>(srcp, dstp, dinv, cursor, csrs, csrn, E);
  gbounds<<<(G+1+255)/256, 256, 0, stream>>>(batch, gstart, N, G);
  prep_w<<<(3*16384+255)/256, 256, 0, stream>>>(W0, W1, W2, Wh, Wl);

  // --- BatchNorm stats: atomic-free two-stage ---
  bn_part<<<BN_BLOCKS, 256, 0, stream>>>(x, part, N*32);
  bn_reduce<<<1, 256, 0, stream>>>(part, gamma, beta, scale, shift, N);

  const float* bs[3] = {b0, b1, b2};
  for (int l = 0; l < 3; ++l){
    const float* src_mat = (l == 0) ? x : h;
    const float* sc = (l == 0) ? scale : nullptr;
    const float* sh = (l == 0) ? shift : nullptr;
    gemm_mfma<<<(N+63)/64, 256, 0, stream>>>(src_mat, Wh + l*16384, Wl + l*16384, sc, sh, m, N);
    gather_squash<<<(N+7)/8, 256, 0, stream>>>(m, rowst, csrs, csrn, dinv, bs[l], tar + l*128, h, attn, N);
    readout<<<G, 1024, 0, stream>>>(h, attn, gstart, grep);
  }
  classify<<<G, 128, 0, stream>>>(grep, l1w, l1b, l2w, l2b, out);
}

// Round 7
// 373.548 us; speedup vs baseline: 1.3981x; 1.1698x over previous
//
#include <hip/hip_runtime.h>
#include <hip/hip_bf16.h>
#include <math.h>

#define BN_EPS 1e-5f
#define SCAN_CHUNK 1024
#define BN_BLOCKS 512

typedef __attribute__((ext_vector_type(8)))  short short8v;
typedef __attribute__((ext_vector_type(16))) float f32x16;

__device__ __forceinline__ unsigned short f2bf(float f){
  union { float f; unsigned u; } v; v.f = f;
  unsigned r = v.u + 0x7FFFu + ((v.u >> 16) & 1u);
  return (unsigned short)(r >> 16);
}
__device__ __forceinline__ float bf2f(unsigned short b){
  union { unsigned u; float f; } v; v.u = ((unsigned)b) << 16;
  return v.f;
}
// unpack 2 bf16 from a u32 (low half = even feat, high half = odd feat)
__device__ __forceinline__ float2 bfpair(unsigned u){
  union { unsigned u; float f; } lo, hi;
  lo.u = u << 16;
  hi.u = u & 0xFFFF0000u;
  return make_float2(lo.f, hi.f);
}

// ---------------- BatchNorm stats, stage 1: per-block partials (NO atomics) ----------------
__global__ __launch_bounds__(256) void bn_part(const float* __restrict__ x,
                                               float* __restrict__ part, int total4){
  const float4* x4 = (const float4*)x;
  int stride = gridDim.x * blockDim.x;
  float4 s = make_float4(0.f,0.f,0.f,0.f);
  float4 q = make_float4(0.f,0.f,0.f,0.f);
  for (int idx = blockIdx.x*blockDim.x + threadIdx.x; idx < total4; idx += stride){
    float4 v = x4[idx];
    s.x += v.x; s.y += v.y; s.z += v.z; s.w += v.w;
    q.x += v.x*v.x; q.y += v.y*v.y; q.z += v.z*v.z; q.w += v.w*v.w;
  }
  __shared__ float4 shs[256], shq[256];
  shs[threadIdx.x] = s; shq[threadIdx.x] = q;
  __syncthreads();
  if (threadIdx.x < 32){
    int c4 = threadIdx.x;
    float4 ts = shs[c4], tq = shq[c4];
    #pragma unroll
    for (int j = 1; j < 8; ++j){
      float4 os = shs[c4 + j*32], oq = shq[c4 + j*32];
      ts.x += os.x; ts.y += os.y; ts.z += os.z; ts.w += os.w;
      tq.x += oq.x; tq.y += oq.y; tq.z += oq.z; tq.w += oq.w;
    }
    float* pb = part + (size_t)blockIdx.x * 256;
    *(float4*)(pb + c4*4)       = ts;
    *(float4*)(pb + 128 + c4*4) = tq;
  }
}

__global__ __launch_bounds__(256) void bn_reduce(const float* __restrict__ part,
                                                 const float* __restrict__ gamma,
                                                 const float* __restrict__ beta,
                                                 float* __restrict__ scale,
                                                 float* __restrict__ shift, int N){
  int t = threadIdx.x;
  float a0=0.f,a1=0.f,a2=0.f,a3=0.f,a4=0.f,a5=0.f,a6=0.f,a7=0.f;
  for (int b = 0; b < BN_BLOCKS; b += 8){
    a0 += part[(size_t)(b+0)*256 + t];
    a1 += part[(size_t)(b+1)*256 + t];
    a2 += part[(size_t)(b+2)*256 + t];
    a3 += part[(size_t)(b+3)*256 + t];
    a4 += part[(size_t)(b+4)*256 + t];
    a5 += part[(size_t)(b+5)*256 + t];
    a6 += part[(size_t)(b+6)*256 + t];
    a7 += part[(size_t)(b+7)*256 + t];
  }
  float acc = ((a0+a1)+(a2+a3)) + ((a4+a5)+(a6+a7));
  __shared__ float sh[256];
  sh[t] = acc;
  __syncthreads();
  if (t < 128){
    float mu  = sh[t] / (float)N;
    float var = sh[t+128] / (float)N - mu*mu;
    float sc  = gamma[t] * rsqrtf(var + BN_EPS);
    scale[t] = sc;
    shift[t] = beta[t] - mu*sc;
  }
}

// ---------------- CSR build ----------------
__global__ void count_deg(const int* __restrict__ dst, int* __restrict__ indeg, int E){
  int e = blockIdx.x*blockDim.x + threadIdx.x;
  if (e < E) atomicAdd(&indeg[dst[e]], 1);
}

__global__ void dinv_k(const int* __restrict__ indeg, float* __restrict__ dinv, int N){
  int v = blockIdx.x*blockDim.x + threadIdx.x;
  if (v < N) dinv[v] = rsqrtf((float)indeg[v] + 1.0f);
}

__global__ __launch_bounds__(256) void scan_part(const int* __restrict__ indeg,
                                                 int* __restrict__ bsum, int N){
  __shared__ int sh[256];
  int base = blockIdx.x * SCAN_CHUNK;
  int s = 0;
  for (int i = threadIdx.x; i < SCAN_CHUNK; i += 256){
    int idx = base + i;
    if (idx < N) s += indeg[idx];
  }
  sh[threadIdx.x] = s; __syncthreads();
  for (int d = 128; d > 0; d >>= 1){
    if (threadIdx.x < d) sh[threadIdx.x] += sh[threadIdx.x + d];
    __syncthreads();
  }
  if (threadIdx.x == 0) bsum[blockIdx.x] = sh[0];
}

__global__ __launch_bounds__(256) void scan_bsum(int* __restrict__ bsum, int nb){
  __shared__ int sh[256];
  int tid = threadIdx.x;
  int v = (tid < nb) ? bsum[tid] : 0;
  sh[tid] = v; __syncthreads();
  for (int d = 1; d < 256; d <<= 1){
    int t = (tid >= d) ? sh[tid-d] : 0;
    __syncthreads();
    sh[tid] += t;
    __syncthreads();
  }
  if (tid < nb) bsum[tid] = sh[tid] - v;
}

__global__ __launch_bounds__(256) void scan_fill(const int* __restrict__ indeg,
                                                 const int* __restrict__ bsum,
                                                 int* __restrict__ rowstart,
                                                 int* __restrict__ cursor, int N){
  __shared__ int sh[256];
  int base = blockIdx.x * SCAN_CHUNK;
  int tid = threadIdx.x;
  int i0 = base + tid*4;
  int v[4]; int s = 0;
  #pragma unroll
  for (int j=0;j<4;j++){
    int idx = i0 + j;
    v[j] = (idx < N) ? indeg[idx] : 0;
    s += v[j];
  }
  sh[tid] = s; __syncthreads();
  for (int d = 1; d < 256; d <<= 1){
    int t = (tid >= d) ? sh[tid-d] : 0;
    __syncthreads();
    sh[tid] += t;
    __syncthreads();
  }
  int off = bsum[blockIdx.x] + sh[tid] - s;
  #pragma unroll
  for (int j=0;j<4;j++){
    int idx = i0 + j;
    if (idx < N){ rowstart[idx] = off; cursor[idx] = off; }
    off += v[j];
  }
  if (blockIdx.x == gridDim.x - 1 && tid == 255) rowstart[N] = off;
}

__global__ void fill_csr(const int* __restrict__ src, const int* __restrict__ dst,
                         const float* __restrict__ dinv, int* __restrict__ cursor,
                         int* __restrict__ csrs, float* __restrict__ csrn, int E){
  int e = blockIdx.x*blockDim.x + threadIdx.x;
  if (e < E){
    int s = src[e], d = dst[e];
    int pos = atomicAdd(&cursor[d], 1);
    csrs[pos] = s;
    csrn[pos] = dinv[s]*dinv[d];
  }
}

__global__ void gbounds(const int* __restrict__ batch, int* __restrict__ gstart, int N, int G){
  int g = blockIdx.x*blockDim.x + threadIdx.x;
  if (g > G) return;
  int lo = 0, hi = N;
  while (lo < hi){ int mid = (lo+hi)>>1; if (batch[mid] < g) lo = mid+1; else hi = mid; }
  gstart[g] = lo;
}

// ---- split W into bf16 hi/lo, transposed layout Wt[l][c][k] ----
__global__ void prep_w(const float* __restrict__ W0, const float* __restrict__ W1,
                       const float* __restrict__ W2, unsigned short* __restrict__ Wh,
                       unsigned short* __restrict__ Wl){
  int idx = blockIdx.x*blockDim.x + threadIdx.x;
  if (idx >= 3*16384) return;
  int l = idx >> 14, r = idx & 16383, c = r >> 7, k = r & 127;
  const float* W = (l==0) ? W0 : (l==1) ? W1 : W2;
  float v = W[k*128 + c];
  unsigned short h = f2bf(v);
  Wh[idx] = h;
  Wl[idx] = f2bf(v - bf2f(h));
}

// ---------------- split-bf16 MFMA GEMM: C[N,128] (bf16) = A[N,128] @ W ----------------
__global__ __launch_bounds__(256) void gemm_mfma(
    const float* __restrict__ A, const unsigned short* __restrict__ Bh,
    const unsigned short* __restrict__ Bl, const float* __restrict__ scale,
    const float* __restrict__ shift, unsigned short* __restrict__ C, int N){
  __shared__ unsigned short Ah[64*128];
  __shared__ unsigned short Al[64*128];
  int tid = threadIdx.x;
  int r0 = blockIdx.x * 64;

  #pragma unroll
  for (int it = 0; it < 8; ++it){
    int idx = tid + it*256;
    int row = idx >> 5;
    int c4  = idx & 31;
    int r = r0 + row;
    float4 av = (r < N) ? *(const float4*)(A + (size_t)r*128 + c4*4)
                        : make_float4(0.f,0.f,0.f,0.f);
    if (scale){
      float4 sc = *(const float4*)(scale + c4*4);
      float4 sh = *(const float4*)(shift + c4*4);
      av.x = av.x*sc.x + sh.x; av.y = av.y*sc.y + sh.y;
      av.z = av.z*sc.z + sh.z; av.w = av.w*sc.w + sh.w;
    }
    float a[4] = {av.x, av.y, av.z, av.w};
    unsigned short hh[4], ll[4];
    #pragma unroll
    for (int j = 0; j < 4; ++j){
      hh[j] = f2bf(a[j]);
      ll[j] = f2bf(a[j] - bf2f(hh[j]));
    }
    int byte0 = (c4*8) ^ ((row & 15) << 4);
    union { unsigned short u[4]; uint2 v; } ph, pl;
    ph.u[0]=hh[0]; ph.u[1]=hh[1]; ph.u[2]=hh[2]; ph.u[3]=hh[3];
    pl.u[0]=ll[0]; pl.u[1]=ll[1]; pl.u[2]=ll[2]; pl.u[3]=ll[3];
    *(uint2*)((char*)Ah + row*256 + byte0) = ph.v;
    *(uint2*)((char*)Al + row*256 + byte0) = pl.v;
  }
  __syncthreads();

  int w = tid >> 6, lane = tid & 63;
  int rt = w & 1;
  int ct = (w >> 1) * 64;
  int lrow = 32*rt + (lane & 31);
  int khalf = lane >> 5;
  int c0 = ct + (lane & 31);

  f32x16 acc0 = {}, acc1 = {};
  const char* AhB = (const char*)Ah + lrow*256;
  const char* AlB = (const char*)Al + lrow*256;
  const unsigned short* bh0 = Bh + (size_t)c0*128 + khalf*8;
  const unsigned short* bl0 = Bl + (size_t)c0*128 + khalf*8;
  int sw = (lrow & 15) << 4;

  #pragma unroll
  for (int s = 0; s < 8; ++s){
    int abyte = (s*32 + khalf*16) ^ sw;
    short8v a_hi = *(const short8v*)(AhB + abyte);
    short8v a_lo = *(const short8v*)(AlB + abyte);
    short8v b_h0 = *(const short8v*)(bh0 + s*16);
    short8v b_l0 = *(const short8v*)(bl0 + s*16);
    short8v b_h1 = *(const short8v*)(bh0 + 32*128 + s*16);
    short8v b_l1 = *(const short8v*)(bl0 + 32*128 + s*16);
    acc0 = __builtin_amdgcn_mfma_f32_32x32x16_bf16(a_hi, b_h0, acc0, 0, 0, 0);
    acc1 = __builtin_amdgcn_mfma_f32_32x32x16_bf16(a_hi, b_h1, acc1, 0, 0, 0);
    acc0 = __builtin_amdgcn_mfma_f32_32x32x16_bf16(a_hi, b_l0, acc0, 0, 0, 0);
    acc1 = __builtin_amdgcn_mfma_f32_32x32x16_bf16(a_hi, b_l1, acc1, 0, 0, 0);
    acc0 = __builtin_amdgcn_mfma_f32_32x32x16_bf16(a_lo, b_h0, acc0, 0, 0, 0);
    acc1 = __builtin_amdgcn_mfma_f32_32x32x16_bf16(a_lo, b_h1, acc1, 0, 0, 0);
  }

  #pragma unroll
  for (int r = 0; r < 16; ++r){
    int row = r0 + 32*rt + (r & 3) + 8*(r >> 2) + 4*khalf;
    if (row < N){
      C[(size_t)row*128 + c0]      = f2bf(acc0[r]);
      C[(size_t)row*128 + c0 + 32] = f2bf(acc1[r]);
    }
  }
}

// ---------------- fused aggregation + bias + squash + attention ----------------
// Half-wave (32 lanes x 4 feats) per node; m is bf16 (256 B/row) to halve gather bytes.
__global__ __launch_bounds__(256) void gather_squash(
    const unsigned short* __restrict__ m, const int* __restrict__ rowstart,
    const int* __restrict__ csrs, const float* __restrict__ csrn,
    const float* __restrict__ dinv, const float* __restrict__ bias,
    const float* __restrict__ tar, float* __restrict__ h, float* __restrict__ attn, int N){
  int node = blockIdx.x*8 + (threadIdx.x >> 5);
  if (node >= N) return;
  int lane = threadIdx.x & 31;
  const uint2* m2 = (const uint2*)m;   // 1 uint2 = 4 bf16 feats
  float dv = dinv[node];
  float sn = dv*dv;
  uint2 sv = m2[(size_t)node*32 + lane];
  float2 p0 = bfpair(sv.x), p1 = bfpair(sv.y);
  float a0 = p0.x*sn, a1 = p0.y*sn, a2 = p1.x*sn, a3 = p1.y*sn;
  int j0 = rowstart[node], j1 = rowstart[node+1];

  for (int base = j0; base < j1; base += 32){
    int cnt = j1 - base; if (cnt > 32) cnt = 32;
    int   sidx = 0; float swt = 0.f;
    if (lane < cnt){ sidx = csrs[base + lane]; swt = csrn[base + lane]; }
    int t = 0;
    for (; t + 4 <= cnt; t += 4){
      int s0 = __shfl(sidx, t, 32),   s1 = __shfl(sidx, t+1, 32);
      int s2 = __shfl(sidx, t+2, 32), s3 = __shfl(sidx, t+3, 32);
      float w0 = __shfl(swt, t, 32),   w1 = __shfl(swt, t+1, 32);
      float w2 = __shfl(swt, t+2, 32), w3 = __shfl(swt, t+3, 32);
      uint2 u0 = m2[(size_t)s0*32 + lane];
      uint2 u1 = m2[(size_t)s1*32 + lane];
      uint2 u2 = m2[(size_t)s2*32 + lane];
      uint2 u3 = m2[(size_t)s3*32 + lane];
      float2 q0, q1;
      q0 = bfpair(u0.x); q1 = bfpair(u0.y);
      a0 += w0*q0.x; a1 += w0*q0.y; a2 += w0*q1.x; a3 += w0*q1.y;
      q0 = bfpair(u1.x); q1 = bfpair(u1.y);
      a0 += w1*q0.x; a1 += w1*q0.y; a2 += w1*q1.x; a3 += w1*q1.y;
      q0 = bfpair(u2.x); q1 = bfpair(u2.y);
      a0 += w2*q0.x; a1 += w2*q0.y; a2 += w2*q1.x; a3 += w2*q1.y;
      q0 = bfpair(u3.x); q1 = bfpair(u3.y);
      a0 += w3*q0.x; a1 += w3*q0.y; a2 += w3*q1.x; a3 += w3*q1.y;
    }
    if (cnt - t >= 2){
      int s0 = __shfl(sidx, t, 32), s1 = __shfl(sidx, t+1, 32);
      float w0 = __shfl(swt, t, 32), w1 = __shfl(swt, t+1, 32);
      uint2 u0 = m2[(size_t)s0*32 + lane];
      uint2 u1 = m2[(size_t)s1*32 + lane];
      float2 q0 = bfpair(u0.x), q1 = bfpair(u0.y);
      a0 += w0*q0.x; a1 += w0*q0.y; a2 += w0*q1.x; a3 += w0*q1.y;
      q0 = bfpair(u1.x); q1 = bfpair(u1.y);
      a0 += w1*q0.x; a1 += w1*q0.y; a2 += w1*q1.x; a3 += w1*q1.y;
      t += 2;
    }
    if (t < cnt){
      int s0 = __shfl(sidx, t, 32);
      float w0 = __shfl(swt, t, 32);
      uint2 u0 = m2[(size_t)s0*32 + lane];
      float2 q0 = bfpair(u0.x), q1 = bfpair(u0.y);
      a0 += w0*q0.x; a1 += w0*q0.y; a2 += w0*q1.x; a3 += w0*q1.y;
    }
  }

  float4 bv = ((const float4*)bias)[lane];
  a0 += bv.x; a1 += bv.y; a2 += bv.z; a3 += bv.w;
  float n2 = a0*a0 + a1*a1 + a2*a2 + a3*a3;
  #pragma unroll
  for (int o = 16; o > 0; o >>= 1) n2 += __shfl_xor(n2, o);
  float sc = (n2/(1.f+n2)) * rsqrtf(n2 + 1e-12f);
  float h0 = a0*sc, h1 = a1*sc, h2 = a2*sc, h3 = a3*sc;
  ((float4*)(h + (size_t)node*128))[lane] = make_float4(h0, h1, h2, h3);
  float4 tv = ((const float4*)tar)[lane];
  float at = h0*tv.x + h1*tv.y + h2*tv.z + h3*tv.w;
  #pragma unroll
  for (int o = 16; o > 0; o >>= 1) at += __shfl_xor(at, o);
  if (lane == 0) attn[node] = at;
}

// ---------------- per-graph readout (wsum / mean / max), accumulated ----------------
__global__ __launch_bounds__(1024) void readout(const float* __restrict__ h,
                                                const float* __restrict__ attn,
                                                const int* __restrict__ gstart,
                                                float* __restrict__ grep){
  int g = blockIdx.x;
  int t   = threadIdx.x & 63;
  int grp = threadIdx.x >> 6;
  int a = gstart[g], b = gstart[g+1];
  float wsx = 0.f, wsy = 0.f, smx_ = 0.f, smy_ = 0.f;
  float mxx = -INFINITY, mxy = -INFINITY;
  for (int n = a + grp; n < b; n += 16){
    float2 v  = ((const float2*)(h + (size_t)n*128))[t];
    float at = attn[n];
    wsx += at*v.x; wsy += at*v.y;
    smx_ += v.x;  smy_ += v.y;
    mxx = fmaxf(mxx, v.x); mxy = fmaxf(mxy, v.y);
  }
  __shared__ float2 sws[16][64], ssm[16][64], smx[16][64];
  sws[grp][t] = make_float2(wsx, wsy);
  ssm[grp][t] = make_float2(smx_, smy_);
  smx[grp][t] = make_float2(mxx, mxy);
  __syncthreads();
  if (grp == 0){
    #pragma unroll
    for (int j = 1; j < 16; ++j){
      float2 ow = sws[j][t], os = ssm[j][t], om = smx[j][t];
      wsx += ow.x; wsy += ow.y;
      smx_ += os.x; smy_ += os.y;
      mxx = fmaxf(mxx, om.x); mxy = fmaxf(mxy, om.y);
    }
    int cnt = b - a;
    float inv = 1.f / fmaxf((float)cnt, 1.f);
    if (cnt == 0){ mxx = 0.f; mxy = 0.f; }
    grep[(size_t)g*384 + t*2]           += wsx;
    grep[(size_t)g*384 + t*2 + 1]       += wsy;
    grep[(size_t)g*384 + 128 + t*2]     += smx_*inv;
    grep[(size_t)g*384 + 128 + t*2 + 1] += smy_*inv;
    grep[(size_t)g*384 + 256 + t*2]     += mxx;
    grep[(size_t)g*384 + 256 + t*2 + 1] += mxy;
  }
}

// ---------------- classifier head + log_softmax ----------------
__global__ __launch_bounds__(128) void classify(const float* __restrict__ grep,
                                                const float* __restrict__ w1, const float* __restrict__ b1,
                                                const float* __restrict__ w2, const float* __restrict__ b2,
                                                float* __restrict__ out){
  int g = blockIdx.x, t = threadIdx.x;
  __shared__ float gr[384];
  for (int i = t; i < 384; i += 128) gr[i] = grep[(size_t)g*384 + i];
  __syncthreads();
  float z = b1[t];
  for (int k = 0; k < 384; ++k) z += gr[k]*w1[k*128 + t];
  z = fmaxf(z, 0.f);
  float c0 = z*w2[t*2 + 0], c1 = z*w2[t*2 + 1];
  #pragma unroll
  for (int o = 32; o > 0; o >>= 1){ c0 += __shfl_xor(c0, o); c1 += __shfl_xor(c1, o); }
  __shared__ float r0s[2], r1s[2];
  if ((t & 63) == 0){ r0s[t>>6] = c0; r1s[t>>6] = c1; }
  __syncthreads();
  if (t == 0){
    float z0 = r0s[0] + r0s[1] + b2[0];
    float z1 = r1s[0] + r1s[1] + b2[1];
    float mm = fmaxf(z0, z1);
    float lse = mm + logf(expf(z0-mm) + expf(z1-mm));
    out[g*2 + 0] = z0 - lse;
    out[g*2 + 1] = z1 - lse;
  }
}

extern "C" void kernel_launch(void* const* d_in, const int* in_sizes, int n_in,
                              void* d_out, int out_size, void* d_ws, size_t ws_size,
                              hipStream_t stream) {
  const float* x     = (const float*)d_in[0];
  const int*   ei    = (const int*)d_in[1];
  const int*   batch = (const int*)d_in[2];
  const float* gamma = (const float*)d_in[3];
  const float* beta  = (const float*)d_in[4];
  const float* W0    = (const float*)d_in[5];
  const float* b0    = (const float*)d_in[6];
  const float* W1    = (const float*)d_in[7];
  const float* b1    = (const float*)d_in[8];
  const float* W2    = (const float*)d_in[9];
  const float* b2    = (const float*)d_in[10];
  const float* tar   = (const float*)d_in[11];
  const float* l1w   = (const float*)d_in[12];
  const float* l1b   = (const float*)d_in[13];
  const float* l2w   = (const float*)d_in[14];
  const float* l2b   = (const float*)d_in[15];
  float* out = (float*)d_out;

  int N = in_sizes[0] / 128;
  int E = in_sizes[1] / 2;
  int G = out_size / 2;
  const int* srcp = ei;
  const int* dstp = ei + E;

  char* wsb = (char*)d_ws;
  size_t off = 0;
  auto alloc = [&](size_t bytes)->char*{
    char* p = wsb + off; off += (bytes + 255) & ~(size_t)255; return p;
  };
  float* h       = (float*)alloc((size_t)N*128*4);
  unsigned short* m = (unsigned short*)alloc((size_t)N*128*2);
  float* attn    = (float*)alloc((size_t)N*4);
  float* dinv    = (float*)alloc((size_t)N*4);
  int*   indeg   = (int*)  alloc((size_t)N*4);
  int*   rowst   = (int*)  alloc((size_t)(N+1)*4);
  int*   cursor  = (int*)  alloc((size_t)N*4);
  int*   csrs    = (int*)  alloc((size_t)E*4);
  float* csrn    = (float*)alloc((size_t)E*4);
  int*   gstart  = (int*)  alloc((size_t)(G+1)*4);
  float* grep    = (float*)alloc((size_t)G*384*4);
  float* stats   = (float*)alloc(2*128*4);
  float* part    = (float*)alloc((size_t)BN_BLOCKS*256*4);
  unsigned short* Wh = (unsigned short*)alloc(3*16384*2);
  unsigned short* Wl = (unsigned short*)alloc(3*16384*2);
  int*   bsum    = (int*)  alloc(256*4);
  (void)ws_size;

  float* scale  = stats;
  float* shift  = stats + 128;

  hipMemsetAsync(indeg, 0, (size_t)N*4, stream);
  hipMemsetAsync(grep, 0, (size_t)G*384*4, stream);

  // --- CSR build first (absorbs first-kernel cold-start) ---
  int nb = (N + SCAN_CHUNK - 1) / SCAN_CHUNK;
  count_deg<<<(E+255)/256, 256, 0, stream>>>(dstp, indeg, E);
  dinv_k<<<(N+255)/256, 256, 0, stream>>>(indeg, dinv, N);
  scan_part<<<nb, 256, 0, stream>>>(indeg, bsum, N);
  scan_bsum<<<1, 256, 0, stream>>>(bsum, nb);
  scan_fill<<<nb, 256, 0, stream>>>(indeg, bsum, rowst, cursor, N);
  fill_csr<<<(E+255)/256, 256, 0, stream>>>(srcp, dstp, dinv, cursor, csrs, csrn, E);
  gbounds<<<(G+1+255)/256, 256, 0, stream>>>(batch, gstart, N, G);
  prep_w<<<(3*16384+255)/256, 256, 0, stream>>>(W0, W1, W2, Wh, Wl);

  // --- BatchNorm stats: atomic-free two-stage ---
  bn_part<<<BN_BLOCKS, 256, 0, stream>>>(x, part, N*32);
  bn_reduce<<<1, 256, 0, stream>>>(part, gamma, beta, scale, shift, N);

  const float* bs[3] = {b0, b1, b2};
  for (int l = 0; l < 3; ++l){
    const float* src_mat = (l == 0) ? x : h;
    const float* sc = (l == 0) ? scale : nullptr;
    const float* sh = (l == 0) ? shift : nullptr;
    gemm_mfma<<<(N+63)/64, 256, 0, stream>>>(src_mat, Wh + l*16384, Wl + l*16384, sc, sh, m, N);
    gather_squash<<<(N+7)/8, 256, 0, stream>>>(m, rowst, csrs, csrn, dinv, bs[l], tar + l*128, h, attn, N);
    readout<<<G, 1024, 0, stream>>>(h, attn, gstart, grep);
  }
  classify<<<G, 128, 0, stream>>>(grep, l1w, l1b, l2w, l2b, out);
}

// Round 8
// 345.595 us; speedup vs baseline: 1.5112x; 1.0809x over previous
//
#include <hip/hip_runtime.h>
#include <hip/hip_bf16.h>
#include <math.h>

#define BN_EPS 1e-5f
#define SCAN_CHUNK 1024
#define BN_BLOCKS 512

typedef __attribute__((ext_vector_type(8)))  short short8v;
typedef __attribute__((ext_vector_type(16))) float f32x16;

__device__ __forceinline__ unsigned short f2bf(float f){
  union { float f; unsigned u; } v; v.f = f;
  unsigned r = v.u + 0x7FFFu + ((v.u >> 16) & 1u);
  return (unsigned short)(r >> 16);
}
__device__ __forceinline__ float bf2f(unsigned short b){
  union { unsigned u; float f; } v; v.u = ((unsigned)b) << 16;
  return v.f;
}
__device__ __forceinline__ float2 bfpair(unsigned u){
  union { unsigned u; float f; } lo, hi;
  lo.u = u << 16;
  hi.u = u & 0xFFFF0000u;
  return make_float2(lo.f, hi.f);
}
__device__ __forceinline__ unsigned packbf(float a, float b){
  return (unsigned)f2bf(a) | ((unsigned)f2bf(b) << 16);
}

// ---------------- BatchNorm stats (two-stage, no atomics) ----------------
__global__ __launch_bounds__(256) void bn_part(const float* __restrict__ x,
                                               float* __restrict__ part, int total4){
  const float4* x4 = (const float4*)x;
  int stride = gridDim.x * blockDim.x;
  float4 s = make_float4(0.f,0.f,0.f,0.f);
  float4 q = make_float4(0.f,0.f,0.f,0.f);
  for (int idx = blockIdx.x*blockDim.x + threadIdx.x; idx < total4; idx += stride){
    float4 v = x4[idx];
    s.x += v.x; s.y += v.y; s.z += v.z; s.w += v.w;
    q.x += v.x*v.x; q.y += v.y*v.y; q.z += v.z*v.z; q.w += v.w*v.w;
  }
  __shared__ float4 shs[256], shq[256];
  shs[threadIdx.x] = s; shq[threadIdx.x] = q;
  __syncthreads();
  if (threadIdx.x < 32){
    int c4 = threadIdx.x;
    float4 ts = shs[c4], tq = shq[c4];
    #pragma unroll
    for (int j = 1; j < 8; ++j){
      float4 os = shs[c4 + j*32], oq = shq[c4 + j*32];
      ts.x += os.x; ts.y += os.y; ts.z += os.z; ts.w += os.w;
      tq.x += oq.x; tq.y += oq.y; tq.z += oq.z; tq.w += oq.w;
    }
    float* pb = part + (size_t)blockIdx.x * 256;
    *(float4*)(pb + c4*4)       = ts;
    *(float4*)(pb + 128 + c4*4) = tq;
  }
}

__global__ __launch_bounds__(256) void bn_reduce(const float* __restrict__ part,
                                                 const float* __restrict__ gamma,
                                                 const float* __restrict__ beta,
                                                 float* __restrict__ scale,
                                                 float* __restrict__ shift, int N){
  int t = threadIdx.x;
  float a0=0.f,a1=0.f,a2=0.f,a3=0.f,a4=0.f,a5=0.f,a6=0.f,a7=0.f;
  for (int b = 0; b < BN_BLOCKS; b += 8){
    a0 += part[(size_t)(b+0)*256 + t];
    a1 += part[(size_t)(b+1)*256 + t];
    a2 += part[(size_t)(b+2)*256 + t];
    a3 += part[(size_t)(b+3)*256 + t];
    a4 += part[(size_t)(b+4)*256 + t];
    a5 += part[(size_t)(b+5)*256 + t];
    a6 += part[(size_t)(b+6)*256 + t];
    a7 += part[(size_t)(b+7)*256 + t];
  }
  float acc = ((a0+a1)+(a2+a3)) + ((a4+a5)+(a6+a7));
  __shared__ float sh[256];
  sh[t] = acc;
  __syncthreads();
  if (t < 128){
    float mu  = sh[t] / (float)N;
    float var = sh[t+128] / (float)N - mu*mu;
    float sc  = gamma[t] * rsqrtf(var + BN_EPS);
    scale[t] = sc;
    shift[t] = beta[t] - mu*sc;
  }
}

// ---------------- CSR build ----------------
__global__ void count_deg(const int* __restrict__ dst, int* __restrict__ indeg, int E){
  int e = blockIdx.x*blockDim.x + threadIdx.x;
  if (e < E) atomicAdd(&indeg[dst[e]], 1);
}

__global__ void dinv_k(const int* __restrict__ indeg, float* __restrict__ dinv, int N){
  int v = blockIdx.x*blockDim.x + threadIdx.x;
  if (v < N) dinv[v] = rsqrtf((float)indeg[v] + 1.0f);
}

__global__ __launch_bounds__(256) void scan_part(const int* __restrict__ indeg,
                                                 int* __restrict__ bsum, int N){
  __shared__ int sh[256];
  int base = blockIdx.x * SCAN_CHUNK;
  int s = 0;
  for (int i = threadIdx.x; i < SCAN_CHUNK; i += 256){
    int idx = base + i;
    if (idx < N) s += indeg[idx];
  }
  sh[threadIdx.x] = s; __syncthreads();
  for (int d = 128; d > 0; d >>= 1){
    if (threadIdx.x < d) sh[threadIdx.x] += sh[threadIdx.x + d];
    __syncthreads();
  }
  if (threadIdx.x == 0) bsum[blockIdx.x] = sh[0];
}

__global__ __launch_bounds__(256) void scan_bsum(int* __restrict__ bsum, int nb){
  __shared__ int sh[256];
  int tid = threadIdx.x;
  int v = (tid < nb) ? bsum[tid] : 0;
  sh[tid] = v; __syncthreads();
  for (int d = 1; d < 256; d <<= 1){
    int t = (tid >= d) ? sh[tid-d] : 0;
    __syncthreads();
    sh[tid] += t;
    __syncthreads();
  }
  if (tid < nb) bsum[tid] = sh[tid] - v;
}

__global__ __launch_bounds__(256) void scan_fill(const int* __restrict__ indeg,
                                                 const int* __restrict__ bsum,
                                                 int* __restrict__ rowstart,
                                                 int* __restrict__ cursor, int N){
  __shared__ int sh[256];
  int base = blockIdx.x * SCAN_CHUNK;
  int tid = threadIdx.x;
  int i0 = base + tid*4;
  int v[4]; int s = 0;
  #pragma unroll
  for (int j=0;j<4;j++){
    int idx = i0 + j;
    v[j] = (idx < N) ? indeg[idx] : 0;
    s += v[j];
  }
  sh[tid] = s; __syncthreads();
  for (int d = 1; d < 256; d <<= 1){
    int t = (tid >= d) ? sh[tid-d] : 0;
    __syncthreads();
    sh[tid] += t;
    __syncthreads();
  }
  int off = bsum[blockIdx.x] + sh[tid] - s;
  #pragma unroll
  for (int j=0;j<4;j++){
    int idx = i0 + j;
    if (idx < N){ rowstart[idx] = off; cursor[idx] = off; }
    off += v[j];
  }
  if (blockIdx.x == gridDim.x - 1 && tid == 255) rowstart[N] = off;
}

// packed edge record: .x = src index, .y = norm (float bits) — ONE scattered store
__global__ void fill_csr(const int* __restrict__ src, const int* __restrict__ dst,
                         const float* __restrict__ dinv, int* __restrict__ cursor,
                         uint2* __restrict__ csre, int E){
  int e = blockIdx.x*blockDim.x + threadIdx.x;
  if (e < E){
    int s = src[e], d = dst[e];
    int pos = atomicAdd(&cursor[d], 1);
    union { float f; unsigned u; } w; w.f = dinv[s]*dinv[d];
    csre[pos] = make_uint2((unsigned)s, w.u);
  }
}

__global__ void gbounds(const int* __restrict__ batch, int* __restrict__ gstart, int N, int G){
  int g = blockIdx.x*blockDim.x + threadIdx.x;
  if (g > G) return;
  int lo = 0, hi = N;
  while (lo < hi){ int mid = (lo+hi)>>1; if (batch[mid] < g) lo = mid+1; else hi = mid; }
  gstart[g] = lo;
}

// ---- split W into bf16 hi/lo, transposed layout Wt[l][c][k] ----
__global__ void prep_w(const float* __restrict__ W0, const float* __restrict__ W1,
                       const float* __restrict__ W2, unsigned short* __restrict__ Wh,
                       unsigned short* __restrict__ Wl){
  int idx = blockIdx.x*blockDim.x + threadIdx.x;
  if (idx >= 3*16384) return;
  int l = idx >> 14, r = idx & 16383, c = r >> 7, k = r & 127;
  const float* W = (l==0) ? W0 : (l==1) ? W1 : W2;
  float v = W[k*128 + c];
  unsigned short h = f2bf(v);
  Wh[idx] = h;
  Wl[idx] = f2bf(v - bf2f(h));
}

// ---------------- MFMA GEMM: C[N,128] (bf16) = A @ W ----------------
// Layer 0: A32 (fp32 + BN) -> split hi/lo, 6 MFMAs/step.
// Layers 1,2: A16 (bf16) -> exact, hi only, 4 MFMAs/step.
__global__ __launch_bounds__(256) void gemm_mfma(
    const float* __restrict__ A32, const unsigned short* __restrict__ A16,
    const unsigned short* __restrict__ Bh, const unsigned short* __restrict__ Bl,
    const float* __restrict__ scale, const float* __restrict__ shift,
    unsigned short* __restrict__ C, int N){
  __shared__ unsigned short Ah[64*128];
  __shared__ unsigned short Al[64*128];
  int tid = threadIdx.x;
  int r0 = blockIdx.x * 64;

  if (A32){
    #pragma unroll
    for (int it = 0; it < 8; ++it){
      int idx = tid + it*256;
      int row = idx >> 5;
      int c4  = idx & 31;
      int r = r0 + row;
      float4 av = (r < N) ? *(const float4*)(A32 + (size_t)r*128 + c4*4)
                          : make_float4(0.f,0.f,0.f,0.f);
      float4 sc = *(const float4*)(scale + c4*4);
      float4 sh = *(const float4*)(shift + c4*4);
      av.x = av.x*sc.x + sh.x; av.y = av.y*sc.y + sh.y;
      av.z = av.z*sc.z + sh.z; av.w = av.w*sc.w + sh.w;
      float a[4] = {av.x, av.y, av.z, av.w};
      unsigned short hh[4], ll[4];
      #pragma unroll
      for (int j = 0; j < 4; ++j){
        hh[j] = f2bf(a[j]);
        ll[j] = f2bf(a[j] - bf2f(hh[j]));
      }
      int byte0 = (c4*8) ^ ((row & 15) << 4);
      union { unsigned short u[4]; uint2 v; } ph, pl;
      ph.u[0]=hh[0]; ph.u[1]=hh[1]; ph.u[2]=hh[2]; ph.u[3]=hh[3];
      pl.u[0]=ll[0]; pl.u[1]=ll[1]; pl.u[2]=ll[2]; pl.u[3]=ll[3];
      *(uint2*)((char*)Ah + row*256 + byte0) = ph.v;
      *(uint2*)((char*)Al + row*256 + byte0) = pl.v;
    }
  } else {
    // bf16 input: straight swizzled copy, 16B per thread-iter
    #pragma unroll
    for (int it = 0; it < 4; ++it){
      int idx = tid + it*256;          // 0..1023 (64 rows x 16 uint4)
      int row = idx >> 4;
      int c8  = idx & 15;              // 8 bf16 per uint4
      int r = r0 + row;
      uint4 v = (r < N) ? *(const uint4*)(A16 + (size_t)r*128 + c8*8)
                        : make_uint4(0,0,0,0);
      int byte0 = (c8*16) ^ ((row & 15) << 4);
      *(uint4*)((char*)Ah + row*256 + byte0) = v;
    }
  }
  __syncthreads();

  int w = tid >> 6, lane = tid & 63;
  int rt = w & 1;
  int ct = (w >> 1) * 64;
  int lrow = 32*rt + (lane & 31);
  int khalf = lane >> 5;
  int c0 = ct + (lane & 31);

  f32x16 acc0 = {}, acc1 = {};
  const char* AhB = (const char*)Ah + lrow*256;
  const char* AlB = (const char*)Al + lrow*256;
  const unsigned short* bh0 = Bh + (size_t)c0*128 + khalf*8;
  const unsigned short* bl0 = Bl + (size_t)c0*128 + khalf*8;
  int sw = (lrow & 15) << 4;

  #pragma unroll
  for (int s = 0; s < 8; ++s){
    int abyte = (s*32 + khalf*16) ^ sw;
    short8v a_hi = *(const short8v*)(AhB + abyte);
    short8v b_h0 = *(const short8v*)(bh0 + s*16);
    short8v b_l0 = *(const short8v*)(bl0 + s*16);
    short8v b_h1 = *(const short8v*)(bh0 + 32*128 + s*16);
    short8v b_l1 = *(const short8v*)(bl0 + 32*128 + s*16);
    acc0 = __builtin_amdgcn_mfma_f32_32x32x16_bf16(a_hi, b_h0, acc0, 0, 0, 0);
    acc1 = __builtin_amdgcn_mfma_f32_32x32x16_bf16(a_hi, b_h1, acc1, 0, 0, 0);
    acc0 = __builtin_amdgcn_mfma_f32_32x32x16_bf16(a_hi, b_l0, acc0, 0, 0, 0);
    acc1 = __builtin_amdgcn_mfma_f32_32x32x16_bf16(a_hi, b_l1, acc1, 0, 0, 0);
    if (A32){
      short8v a_lo = *(const short8v*)(AlB + abyte);
      acc0 = __builtin_amdgcn_mfma_f32_32x32x16_bf16(a_lo, b_h0, acc0, 0, 0, 0);
      acc1 = __builtin_amdgcn_mfma_f32_32x32x16_bf16(a_lo, b_h1, acc1, 0, 0, 0);
    }
  }

  #pragma unroll
  for (int r = 0; r < 16; ++r){
    int row = r0 + 32*rt + (r & 3) + 8*(r >> 2) + 4*khalf;
    if (row < N){
      C[(size_t)row*128 + c0]      = f2bf(acc0[r]);
      C[(size_t)row*128 + c0 + 32] = f2bf(acc1[r]);
    }
  }
}

// ---------------- fused aggregation + bias + squash + attention ----------------
// Half-wave (32 lanes x 4 feats) per node; m bf16 gather; h written bf16.
__global__ __launch_bounds__(256) void gather_squash(
    const unsigned short* __restrict__ m, const int* __restrict__ rowstart,
    const uint2* __restrict__ csre, const float* __restrict__ dinv,
    const float* __restrict__ bias, const float* __restrict__ tar,
    unsigned short* __restrict__ h, float* __restrict__ attn, int N){
  int node = blockIdx.x*8 + (threadIdx.x >> 5);
  if (node >= N) return;
  int lane = threadIdx.x & 31;
  const uint2* m2 = (const uint2*)m;
  float dv = dinv[node];
  float sn = dv*dv;
  uint2 sv = m2[(size_t)node*32 + lane];
  float2 p0 = bfpair(sv.x), p1 = bfpair(sv.y);
  float a0 = p0.x*sn, a1 = p0.y*sn, a2 = p1.x*sn, a3 = p1.y*sn;
  int j0 = rowstart[node], j1 = rowstart[node+1];

  for (int base = j0; base < j1; base += 32){
    int cnt = j1 - base; if (cnt > 32) cnt = 32;
    int sidx = 0; float swt = 0.f;
    if (lane < cnt){
      uint2 ce = csre[base + lane];
      sidx = (int)ce.x;
      union { unsigned u; float f; } wv; wv.u = ce.y;
      swt = wv.f;
    }
    int t = 0;
    for (; t + 4 <= cnt; t += 4){
      int s0 = __shfl(sidx, t, 32),   s1 = __shfl(sidx, t+1, 32);
      int s2 = __shfl(sidx, t+2, 32), s3 = __shfl(sidx, t+3, 32);
      float w0 = __shfl(swt, t, 32),   w1 = __shfl(swt, t+1, 32);
      float w2 = __shfl(swt, t+2, 32), w3 = __shfl(swt, t+3, 32);
      uint2 u0 = m2[(size_t)s0*32 + lane];
      uint2 u1 = m2[(size_t)s1*32 + lane];
      uint2 u2 = m2[(size_t)s2*32 + lane];
      uint2 u3 = m2[(size_t)s3*32 + lane];
      float2 q0, q1;
      q0 = bfpair(u0.x); q1 = bfpair(u0.y);
      a0 += w0*q0.x; a1 += w0*q0.y; a2 += w0*q1.x; a3 += w0*q1.y;
      q0 = bfpair(u1.x); q1 = bfpair(u1.y);
      a0 += w1*q0.x; a1 += w1*q0.y; a2 += w1*q1.x; a3 += w1*q1.y;
      q0 = bfpair(u2.x); q1 = bfpair(u2.y);
      a0 += w2*q0.x; a1 += w2*q0.y; a2 += w2*q1.x; a3 += w2*q1.y;
      q0 = bfpair(u3.x); q1 = bfpair(u3.y);
      a0 += w3*q0.x; a1 += w3*q0.y; a2 += w3*q1.x; a3 += w3*q1.y;
    }
    if (cnt - t >= 2){
      int s0 = __shfl(sidx, t, 32), s1 = __shfl(sidx, t+1, 32);
      float w0 = __shfl(swt, t, 32), w1 = __shfl(swt, t+1, 32);
      uint2 u0 = m2[(size_t)s0*32 + lane];
      uint2 u1 = m2[(size_t)s1*32 + lane];
      float2 q0 = bfpair(u0.x), q1 = bfpair(u0.y);
      a0 += w0*q0.x; a1 += w0*q0.y; a2 += w0*q1.x; a3 += w0*q1.y;
      q0 = bfpair(u1.x); q1 = bfpair(u1.y);
      a0 += w1*q0.x; a1 += w1*q0.y; a2 += w1*q1.x; a3 += w1*q1.y;
      t += 2;
    }
    if (t < cnt){
      int s0 = __shfl(sidx, t, 32);
      float w0 = __shfl(swt, t, 32);
      uint2 u0 = m2[(size_t)s0*32 + lane];
      float2 q0 = bfpair(u0.x), q1 = bfpair(u0.y);
      a0 += w0*q0.x; a1 += w0*q0.y; a2 += w0*q1.x; a3 += w0*q1.y;
    }
  }

  float4 bv = ((const float4*)bias)[lane];
  a0 += bv.x; a1 += bv.y; a2 += bv.z; a3 += bv.w;
  float n2 = a0*a0 + a1*a1 + a2*a2 + a3*a3;
  #pragma unroll
  for (int o = 16; o > 0; o >>= 1) n2 += __shfl_xor(n2, o);
  float sc = (n2/(1.f+n2)) * rsqrtf(n2 + 1e-12f);
  float h0 = a0*sc, h1 = a1*sc, h2 = a2*sc, h3 = a3*sc;
  ((uint2*)(h + (size_t)node*128))[lane] = make_uint2(packbf(h0,h1), packbf(h2,h3));
  float4 tv = ((const float4*)tar)[lane];
  float at = h0*tv.x + h1*tv.y + h2*tv.z + h3*tv.w;
  #pragma unroll
  for (int o = 16; o > 0; o >>= 1) at += __shfl_xor(at, o);
  if (lane == 0) attn[node] = at;
}

// ---------------- per-graph readout (wsum / mean / max), accumulated ----------------
__global__ __launch_bounds__(1024) void readout(const unsigned short* __restrict__ h,
                                                const float* __restrict__ attn,
                                                const int* __restrict__ gstart,
                                                float* __restrict__ grep){
  int g = blockIdx.x;
  int t   = threadIdx.x & 63;   // bf16 pair (feats 2t, 2t+1)
  int grp = threadIdx.x >> 6;
  int a = gstart[g], b = gstart[g+1];
  float wsx = 0.f, wsy = 0.f, smx_ = 0.f, smy_ = 0.f;
  float mxx = -INFINITY, mxy = -INFINITY;
  for (int n = a + grp; n < b; n += 16){
    unsigned u = ((const unsigned*)(h + (size_t)n*128))[t];
    float2 v = bfpair(u);
    float at = attn[n];
    wsx += at*v.x; wsy += at*v.y;
    smx_ += v.x;  smy_ += v.y;
    mxx = fmaxf(mxx, v.x); mxy = fmaxf(mxy, v.y);
  }
  __shared__ float2 sws[16][64], ssm[16][64], smx[16][64];
  sws[grp][t] = make_float2(wsx, wsy);
  ssm[grp][t] = make_float2(smx_, smy_);
  smx[grp][t] = make_float2(mxx, mxy);
  __syncthreads();
  if (grp == 0){
    #pragma unroll
    for (int j = 1; j < 16; ++j){
      float2 ow = sws[j][t], os = ssm[j][t], om = smx[j][t];
      wsx += ow.x; wsy += ow.y;
      smx_ += os.x; smy_ += os.y;
      mxx = fmaxf(mxx, om.x); mxy = fmaxf(mxy, om.y);
    }
    int cnt = b - a;
    float inv = 1.f / fmaxf((float)cnt, 1.f);
    if (cnt == 0){ mxx = 0.f; mxy = 0.f; }
    grep[(size_t)g*384 + t*2]           += wsx;
    grep[(size_t)g*384 + t*2 + 1]       += wsy;
    grep[(size_t)g*384 + 128 + t*2]     += smx_*inv;
    grep[(size_t)g*384 + 128 + t*2 + 1] += smy_*inv;
    grep[(size_t)g*384 + 256 + t*2]     += mxx;
    grep[(size_t)g*384 + 256 + t*2 + 1] += mxy;
  }
}

// ---------------- classifier head + log_softmax ----------------
__global__ __launch_bounds__(128) void classify(const float* __restrict__ grep,
                                                const float* __restrict__ w1, const float* __restrict__ b1,
                                                const float* __restrict__ w2, const float* __restrict__ b2,
                                                float* __restrict__ out){
  int g = blockIdx.x, t = threadIdx.x;
  __shared__ float gr[384];
  for (int i = t; i < 384; i += 128) gr[i] = grep[(size_t)g*384 + i];
  __syncthreads();
  float z = b1[t];
  for (int k = 0; k < 384; ++k) z += gr[k]*w1[k*128 + t];
  z = fmaxf(z, 0.f);
  float c0 = z*w2[t*2 + 0], c1 = z*w2[t*2 + 1];
  #pragma unroll
  for (int o = 32; o > 0; o >>= 1){ c0 += __shfl_xor(c0, o); c1 += __shfl_xor(c1, o); }
  __shared__ float r0s[2], r1s[2];
  if ((t & 63) == 0){ r0s[t>>6] = c0; r1s[t>>6] = c1; }
  __syncthreads();
  if (t == 0){
    float z0 = r0s[0] + r0s[1] + b2[0];
    float z1 = r1s[0] + r1s[1] + b2[1];
    float mm = fmaxf(z0, z1);
    float lse = mm + logf(expf(z0-mm) + expf(z1-mm));
    out[g*2 + 0] = z0 - lse;
    out[g*2 + 1] = z1 - lse;
  }
}

extern "C" void kernel_launch(void* const* d_in, const int* in_sizes, int n_in,
                              void* d_out, int out_size, void* d_ws, size_t ws_size,
                              hipStream_t stream) {
  const float* x     = (const float*)d_in[0];
  const int*   ei    = (const int*)d_in[1];
  const int*   batch = (const int*)d_in[2];
  const float* gamma = (const float*)d_in[3];
  const float* beta  = (const float*)d_in[4];
  const float* W0    = (const float*)d_in[5];
  const float* b0    = (const float*)d_in[6];
  const float* W1    = (const float*)d_in[7];
  const float* b1    = (const float*)d_in[8];
  const float* W2    = (const float*)d_in[9];
  const float* b2    = (const float*)d_in[10];
  const float* tar   = (const float*)d_in[11];
  const float* l1w   = (const float*)d_in[12];
  const float* l1b   = (const float*)d_in[13];
  const float* l2w   = (const float*)d_in[14];
  const float* l2b   = (const float*)d_in[15];
  float* out = (float*)d_out;

  int N = in_sizes[0] / 128;
  int E = in_sizes[1] / 2;
  int G = out_size / 2;
  const int* srcp = ei;
  const int* dstp = ei + E;

  char* wsb = (char*)d_ws;
  size_t off = 0;
  auto alloc = [&](size_t bytes)->char*{
    char* p = wsb + off; off += (bytes + 255) & ~(size_t)255; return p;
  };
  unsigned short* h = (unsigned short*)alloc((size_t)N*128*2);
  unsigned short* m = (unsigned short*)alloc((size_t)N*128*2);
  float* attn    = (float*)alloc((size_t)N*4);
  float* dinv    = (float*)alloc((size_t)N*4);
  int*   indeg   = (int*)  alloc((size_t)N*4);
  int*   rowst   = (int*)  alloc((size_t)(N+1)*4);
  int*   cursor  = (int*)  alloc((size_t)N*4);
  uint2* csre    = (uint2*)alloc((size_t)E*8);
  int*   gstart  = (int*)  alloc((size_t)(G+1)*4);
  float* grep    = (float*)alloc((size_t)G*384*4);
  float* stats   = (float*)alloc(2*128*4);
  float* part    = (float*)alloc((size_t)BN_BLOCKS*256*4);
  unsigned short* Wh = (unsigned short*)alloc(3*16384*2);
  unsigned short* Wl = (unsigned short*)alloc(3*16384*2);
  int*   bsum    = (int*)  alloc(256*4);
  (void)ws_size;

  float* scale  = stats;
  float* shift  = stats + 128;

  hipMemsetAsync(indeg, 0, (size_t)N*4, stream);
  hipMemsetAsync(grep, 0, (size_t)G*384*4, stream);

  // --- CSR build first (absorbs first-kernel cold-start) ---
  int nb = (N + SCAN_CHUNK - 1) / SCAN_CHUNK;
  count_deg<<<(E+255)/256, 256, 0, stream>>>(dstp, indeg, E);
  dinv_k<<<(N+255)/256, 256, 0, stream>>>(indeg, dinv, N);
  scan_part<<<nb, 256, 0, stream>>>(indeg, bsum, N);
  scan_bsum<<<1, 256, 0, stream>>>(bsum, nb);
  scan_fill<<<nb, 256, 0, stream>>>(indeg, bsum, rowst, cursor, N);
  fill_csr<<<(E+255)/256, 256, 0, stream>>>(srcp, dstp, dinv, cursor, csre, E);
  gbounds<<<(G+1+255)/256, 256, 0, stream>>>(batch, gstart, N, G);
  prep_w<<<(3*16384+255)/256, 256, 0, stream>>>(W0, W1, W2, Wh, Wl);

  // --- BatchNorm stats: atomic-free two-stage ---
  bn_part<<<BN_BLOCKS, 256, 0, stream>>>(x, part, N*32);
  bn_reduce<<<1, 256, 0, stream>>>(part, gamma, beta, scale, shift, N);

  const float* bs[3] = {b0, b1, b2};
  for (int l = 0; l < 3; ++l){
    const float* a32 = (l == 0) ? x : nullptr;
    const unsigned short* a16 = (l == 0) ? nullptr : h;
    gemm_mfma<<<(N+63)/64, 256, 0, stream>>>(a32, a16, Wh + l*16384, Wl + l*16384, scale, shift, m, N);
    gather_squash<<<(N+7)/8, 256, 0, stream>>>(m, rowst, csre, dinv, bs[l], tar + l*128, h, attn, N);
    readout<<<G, 1024, 0, stream>>>(h, attn, gstart, grep);
  }
  classify<<<G, 128, 0, stream>>>(grep, l1w, l1b, l2w, l2b, out);
}

// Round 9
// 323.091 us; speedup vs baseline: 1.6164x; 1.0697x over previous
//
#include <hip/hip_runtime.h>
#include <hip/hip_bf16.h>
#include <math.h>

#define BN_EPS 1e-5f
#define SCAN_CHUNK 1024
#define BN_BLOCKS 512

typedef __attribute__((ext_vector_type(8)))  short short8v;
typedef __attribute__((ext_vector_type(16))) float f32x16;

__device__ __forceinline__ unsigned short f2bf(float f){
  union { float f; unsigned u; } v; v.f = f;
  unsigned r = v.u + 0x7FFFu + ((v.u >> 16) & 1u);
  return (unsigned short)(r >> 16);
}
__device__ __forceinline__ float bf2f(unsigned short b){
  union { unsigned u; float f; } v; v.u = ((unsigned)b) << 16;
  return v.f;
}
__device__ __forceinline__ float2 bfpair(unsigned u){
  union { unsigned u; float f; } lo, hi;
  lo.u = u << 16;
  hi.u = u & 0xFFFF0000u;
  return make_float2(lo.f, hi.f);
}
__device__ __forceinline__ unsigned packbf(float a, float b){
  return (unsigned)f2bf(a) | ((unsigned)f2bf(b) << 16);
}

// ---------------- BatchNorm stats (two-stage, no atomics) ----------------
__global__ __launch_bounds__(256) void bn_part(const float* __restrict__ x,
                                               float* __restrict__ part, int total4){
  const float4* x4 = (const float4*)x;
  int stride = gridDim.x * blockDim.x;
  float4 s = make_float4(0.f,0.f,0.f,0.f);
  float4 q = make_float4(0.f,0.f,0.f,0.f);
  for (int idx = blockIdx.x*blockDim.x + threadIdx.x; idx < total4; idx += stride){
    float4 v = x4[idx];
    s.x += v.x; s.y += v.y; s.z += v.z; s.w += v.w;
    q.x += v.x*v.x; q.y += v.y*v.y; q.z += v.z*v.z; q.w += v.w*v.w;
  }
  __shared__ float4 shs[256], shq[256];
  shs[threadIdx.x] = s; shq[threadIdx.x] = q;
  __syncthreads();
  if (threadIdx.x < 32){
    int c4 = threadIdx.x;
    float4 ts = shs[c4], tq = shq[c4];
    #pragma unroll
    for (int j = 1; j < 8; ++j){
      float4 os = shs[c4 + j*32], oq = shq[c4 + j*32];
      ts.x += os.x; ts.y += os.y; ts.z += os.z; ts.w += os.w;
      tq.x += oq.x; tq.y += oq.y; tq.z += oq.z; tq.w += oq.w;
    }
    float* pb = part + (size_t)blockIdx.x * 256;
    *(float4*)(pb + c4*4)       = ts;
    *(float4*)(pb + 128 + c4*4) = tq;
  }
}

__global__ __launch_bounds__(256) void bn_reduce(const float* __restrict__ part,
                                                 const float* __restrict__ gamma,
                                                 const float* __restrict__ beta,
                                                 float* __restrict__ scale,
                                                 float* __restrict__ shift, int N){
  int t = threadIdx.x;
  float a0=0.f,a1=0.f,a2=0.f,a3=0.f,a4=0.f,a5=0.f,a6=0.f,a7=0.f;
  for (int b = 0; b < BN_BLOCKS; b += 8){
    a0 += part[(size_t)(b+0)*256 + t];
    a1 += part[(size_t)(b+1)*256 + t];
    a2 += part[(size_t)(b+2)*256 + t];
    a3 += part[(size_t)(b+3)*256 + t];
    a4 += part[(size_t)(b+4)*256 + t];
    a5 += part[(size_t)(b+5)*256 + t];
    a6 += part[(size_t)(b+6)*256 + t];
    a7 += part[(size_t)(b+7)*256 + t];
  }
  float acc = ((a0+a1)+(a2+a3)) + ((a4+a5)+(a6+a7));
  __shared__ float sh[256];
  sh[t] = acc;
  __syncthreads();
  if (t < 128){
    float mu  = sh[t] / (float)N;
    float var = sh[t+128] / (float)N - mu*mu;
    float sc  = gamma[t] * rsqrtf(var + BN_EPS);
    scale[t] = sc;
    shift[t] = beta[t] - mu*sc;
  }
}

// ---------------- CSR build ----------------
__global__ void count_deg(const int* __restrict__ dst, int* __restrict__ indeg, int E){
  int e = blockIdx.x*blockDim.x + threadIdx.x;
  if (e < E) atomicAdd(&indeg[dst[e]], 1);
}

__global__ void dinv_k(const int* __restrict__ indeg, float* __restrict__ dinv, int N){
  int v = blockIdx.x*blockDim.x + threadIdx.x;
  if (v < N) dinv[v] = rsqrtf((float)indeg[v] + 1.0f);
}

__global__ __launch_bounds__(256) void scan_part(const int* __restrict__ indeg,
                                                 int* __restrict__ bsum, int N){
  __shared__ int sh[256];
  int base = blockIdx.x * SCAN_CHUNK;
  int s = 0;
  for (int i = threadIdx.x; i < SCAN_CHUNK; i += 256){
    int idx = base + i;
    if (idx < N) s += indeg[idx];
  }
  sh[threadIdx.x] = s; __syncthreads();
  for (int d = 128; d > 0; d >>= 1){
    if (threadIdx.x < d) sh[threadIdx.x] += sh[threadIdx.x + d];
    __syncthreads();
  }
  if (threadIdx.x == 0) bsum[blockIdx.x] = sh[0];
}

__global__ __launch_bounds__(256) void scan_bsum(int* __restrict__ bsum, int nb){
  __shared__ int sh[256];
  int tid = threadIdx.x;
  int v = (tid < nb) ? bsum[tid] : 0;
  sh[tid] = v; __syncthreads();
  for (int d = 1; d < 256; d <<= 1){
    int t = (tid >= d) ? sh[tid-d] : 0;
    __syncthreads();
    sh[tid] += t;
    __syncthreads();
  }
  if (tid < nb) bsum[tid] = sh[tid] - v;
}

__global__ __launch_bounds__(256) void scan_fill(const int* __restrict__ indeg,
                                                 const int* __restrict__ bsum,
                                                 int* __restrict__ rowstart,
                                                 int* __restrict__ cursor, int N){
  __shared__ int sh[256];
  int base = blockIdx.x * SCAN_CHUNK;
  int tid = threadIdx.x;
  int i0 = base + tid*4;
  int v[4]; int s = 0;
  #pragma unroll
  for (int j=0;j<4;j++){
    int idx = i0 + j;
    v[j] = (idx < N) ? indeg[idx] : 0;
    s += v[j];
  }
  sh[tid] = s; __syncthreads();
  for (int d = 1; d < 256; d <<= 1){
    int t = (tid >= d) ? sh[tid-d] : 0;
    __syncthreads();
    sh[tid] += t;
    __syncthreads();
  }
  int off = bsum[blockIdx.x] + sh[tid] - s;
  #pragma unroll
  for (int j=0;j<4;j++){
    int idx = i0 + j;
    if (idx < N){ rowstart[idx] = off; cursor[idx] = off; }
    off += v[j];
  }
  if (blockIdx.x == gridDim.x - 1 && tid == 255) rowstart[N] = off;
}

// packed edge record: .x = src index, .y = norm (float bits)
__global__ void fill_csr(const int* __restrict__ src, const int* __restrict__ dst,
                         const float* __restrict__ dinv, int* __restrict__ cursor,
                         uint2* __restrict__ csre, int E){
  int e = blockIdx.x*blockDim.x + threadIdx.x;
  if (e < E){
    int s = src[e], d = dst[e];
    int pos = atomicAdd(&cursor[d], 1);
    union { float f; unsigned u; } w; w.f = dinv[s]*dinv[d];
    csre[pos] = make_uint2((unsigned)s, w.u);
  }
}

__global__ void gbounds(const int* __restrict__ batch, int* __restrict__ gstart, int N, int G){
  int g = blockIdx.x*blockDim.x + threadIdx.x;
  if (g > G) return;
  int lo = 0, hi = N;
  while (lo < hi){ int mid = (lo+hi)>>1; if (batch[mid] < g) lo = mid+1; else hi = mid; }
  gstart[g] = lo;
}

// ---- split W into bf16 hi/lo, transposed layout Wt[l][c][k] ----
__global__ void prep_w(const float* __restrict__ W0, const float* __restrict__ W1,
                       const float* __restrict__ W2, unsigned short* __restrict__ Wh,
                       unsigned short* __restrict__ Wl){
  int idx = blockIdx.x*blockDim.x + threadIdx.x;
  if (idx >= 3*16384) return;
  int l = idx >> 14, r = idx & 16383, c = r >> 7, k = r & 127;
  const float* W = (l==0) ? W0 : (l==1) ? W1 : W2;
  float v = W[k*128 + c];
  unsigned short h = f2bf(v);
  Wh[idx] = h;
  Wl[idx] = f2bf(v - bf2f(h));
}

// ---------------- MFMA GEMM: C[N,128] (bf16) = A @ W ----------------
// MODE 0 (layer 0): fp32 A + fused BN -> split A hi/lo + split W -> 6 MFMA/step.
// MODE 1 (layers 1,2): bf16 A exact, W_hi only -> 2 MFMA/step, 16 KB LDS.
// All B fragments preloaded to VGPRs before A staging (latency overlap).
template<int MODE>
__global__ __launch_bounds__(256) void gemm_mfma(
    const float* __restrict__ A32, const unsigned short* __restrict__ A16,
    const unsigned short* __restrict__ Bh, const unsigned short* __restrict__ Bl,
    const float* __restrict__ scale, const float* __restrict__ shift,
    unsigned short* __restrict__ C, int N){
  __shared__ unsigned short Ah[64*128];
  __shared__ unsigned short Al[MODE == 0 ? 64*128 : 64];
  int tid = threadIdx.x;
  int r0 = blockIdx.x * 64;

  int w = tid >> 6, lane = tid & 63;
  int rt = w & 1;
  int ct = (w >> 1) * 64;
  int lrow = 32*rt + (lane & 31);
  int khalf = lane >> 5;
  int c0 = ct + (lane & 31);
  const unsigned short* bh0 = Bh + (size_t)c0*128 + khalf*8;
  const unsigned short* bl0 = Bl + (size_t)c0*128 + khalf*8;

  // ---- preload B fragments (issued before A staging; complete under it) ----
  short8v bhf[8][2];
  #pragma unroll
  for (int s = 0; s < 8; ++s){
    bhf[s][0] = *(const short8v*)(bh0 + s*16);
    bhf[s][1] = *(const short8v*)(bh0 + 32*128 + s*16);
  }
  short8v blf[MODE == 0 ? 8 : 1][2];
  if (MODE == 0){
    #pragma unroll
    for (int s = 0; s < 8; ++s){
      blf[s][0] = *(const short8v*)(bl0 + s*16);
      blf[s][1] = *(const short8v*)(bl0 + 32*128 + s*16);
    }
  }

  // ---- stage A into LDS (swizzled) ----
  if (MODE == 0){
    #pragma unroll
    for (int it = 0; it < 8; ++it){
      int idx = tid + it*256;
      int row = idx >> 5;
      int c4  = idx & 31;
      int r = r0 + row;
      float4 av = (r < N) ? *(const float4*)(A32 + (size_t)r*128 + c4*4)
                          : make_float4(0.f,0.f,0.f,0.f);
      float4 sc = *(const float4*)(scale + c4*4);
      float4 sh = *(const float4*)(shift + c4*4);
      av.x = av.x*sc.x + sh.x; av.y = av.y*sc.y + sh.y;
      av.z = av.z*sc.z + sh.z; av.w = av.w*sc.w + sh.w;
      float a[4] = {av.x, av.y, av.z, av.w};
      unsigned short hh[4], ll[4];
      #pragma unroll
      for (int j = 0; j < 4; ++j){
        hh[j] = f2bf(a[j]);
        ll[j] = f2bf(a[j] - bf2f(hh[j]));
      }
      int byte0 = (c4*8) ^ ((row & 15) << 4);
      union { unsigned short u[4]; uint2 v; } ph, pl;
      ph.u[0]=hh[0]; ph.u[1]=hh[1]; ph.u[2]=hh[2]; ph.u[3]=hh[3];
      pl.u[0]=ll[0]; pl.u[1]=ll[1]; pl.u[2]=ll[2]; pl.u[3]=ll[3];
      *(uint2*)((char*)Ah + row*256 + byte0) = ph.v;
      *(uint2*)((char*)Al + row*256 + byte0) = pl.v;
    }
  } else {
    #pragma unroll
    for (int it = 0; it < 4; ++it){
      int idx = tid + it*256;
      int row = idx >> 4;
      int c8  = idx & 15;
      int r = r0 + row;
      uint4 v = (r < N) ? *(const uint4*)(A16 + (size_t)r*128 + c8*8)
                        : make_uint4(0,0,0,0);
      int byte0 = (c8*16) ^ ((row & 15) << 4);
      *(uint4*)((char*)Ah + row*256 + byte0) = v;
    }
  }
  __syncthreads();

  f32x16 acc0 = {}, acc1 = {};
  const char* AhB = (const char*)Ah + lrow*256;
  const char* AlB = (const char*)Al + lrow*256;
  int sw = (lrow & 15) << 4;

  #pragma unroll
  for (int s = 0; s < 8; ++s){
    int abyte = (s*32 + khalf*16) ^ sw;
    short8v a_hi = *(const short8v*)(AhB + abyte);
    acc0 = __builtin_amdgcn_mfma_f32_32x32x16_bf16(a_hi, bhf[s][0], acc0, 0, 0, 0);
    acc1 = __builtin_amdgcn_mfma_f32_32x32x16_bf16(a_hi, bhf[s][1], acc1, 0, 0, 0);
    if (MODE == 0){
      short8v a_lo = *(const short8v*)(AlB + abyte);
      acc0 = __builtin_amdgcn_mfma_f32_32x32x16_bf16(a_hi, blf[s][0], acc0, 0, 0, 0);
      acc1 = __builtin_amdgcn_mfma_f32_32x32x16_bf16(a_hi, blf[s][1], acc1, 0, 0, 0);
      acc0 = __builtin_amdgcn_mfma_f32_32x32x16_bf16(a_lo, bhf[s][0], acc0, 0, 0, 0);
      acc1 = __builtin_amdgcn_mfma_f32_32x32x16_bf16(a_lo, bhf[s][1], acc1, 0, 0, 0);
    }
  }

  #pragma unroll
  for (int r = 0; r < 16; ++r){
    int row = r0 + 32*rt + (r & 3) + 8*(r >> 2) + 4*khalf;
    if (row < N){
      C[(size_t)row*128 + c0]      = f2bf(acc0[r]);
      C[(size_t)row*128 + c0 + 32] = f2bf(acc1[r]);
    }
  }
}

// ---------------- fused aggregation + bias + squash + attention ----------------
__global__ __launch_bounds__(256) void gather_squash(
    const unsigned short* __restrict__ m, const int* __restrict__ rowstart,
    const uint2* __restrict__ csre, const float* __restrict__ dinv,
    const float* __restrict__ bias, const float* __restrict__ tar,
    unsigned short* __restrict__ h, float* __restrict__ attn, int N){
  int node = blockIdx.x*8 + (threadIdx.x >> 5);
  if (node >= N) return;
  int lane = threadIdx.x & 31;
  const uint2* m2 = (const uint2*)m;
  float dv = dinv[node];
  float sn = dv*dv;
  uint2 sv = m2[(size_t)node*32 + lane];
  float2 p0 = bfpair(sv.x), p1 = bfpair(sv.y);
  float a0 = p0.x*sn, a1 = p0.y*sn, a2 = p1.x*sn, a3 = p1.y*sn;
  int j0 = rowstart[node], j1 = rowstart[node+1];

  for (int base = j0; base < j1; base += 32){
    int cnt = j1 - base; if (cnt > 32) cnt = 32;
    int sidx = 0; float swt = 0.f;
    if (lane < cnt){
      uint2 ce = csre[base + lane];
      sidx = (int)ce.x;
      union { unsigned u; float f; } wv; wv.u = ce.y;
      swt = wv.f;
    }
    int t = 0;
    for (; t + 4 <= cnt; t += 4){
      int s0 = __shfl(sidx, t, 32),   s1 = __shfl(sidx, t+1, 32);
      int s2 = __shfl(sidx, t+2, 32), s3 = __shfl(sidx, t+3, 32);
      float w0 = __shfl(swt, t, 32),   w1 = __shfl(swt, t+1, 32);
      float w2 = __shfl(swt, t+2, 32), w3 = __shfl(swt, t+3, 32);
      uint2 u0 = m2[(size_t)s0*32 + lane];
      uint2 u1 = m2[(size_t)s1*32 + lane];
      uint2 u2 = m2[(size_t)s2*32 + lane];
      uint2 u3 = m2[(size_t)s3*32 + lane];
      float2 q0, q1;
      q0 = bfpair(u0.x); q1 = bfpair(u0.y);
      a0 += w0*q0.x; a1 += w0*q0.y; a2 += w0*q1.x; a3 += w0*q1.y;
      q0 = bfpair(u1.x); q1 = bfpair(u1.y);
      a0 += w1*q0.x; a1 += w1*q0.y; a2 += w1*q1.x; a3 += w1*q1.y;
      q0 = bfpair(u2.x); q1 = bfpair(u2.y);
      a0 += w2*q0.x; a1 += w2*q0.y; a2 += w2*q1.x; a3 += w2*q1.y;
      q0 = bfpair(u3.x); q1 = bfpair(u3.y);
      a0 += w3*q0.x; a1 += w3*q0.y; a2 += w3*q1.x; a3 += w3*q1.y;
    }
    if (cnt - t >= 2){
      int s0 = __shfl(sidx, t, 32), s1 = __shfl(sidx, t+1, 32);
      float w0 = __shfl(swt, t, 32), w1 = __shfl(swt, t+1, 32);
      uint2 u0 = m2[(size_t)s0*32 + lane];
      uint2 u1 = m2[(size_t)s1*32 + lane];
      float2 q0 = bfpair(u0.x), q1 = bfpair(u0.y);
      a0 += w0*q0.x; a1 += w0*q0.y; a2 += w0*q1.x; a3 += w0*q1.y;
      q0 = bfpair(u1.x); q1 = bfpair(u1.y);
      a0 += w1*q0.x; a1 += w1*q0.y; a2 += w1*q1.x; a3 += w1*q1.y;
      t += 2;
    }
    if (t < cnt){
      int s0 = __shfl(sidx, t, 32);
      float w0 = __shfl(swt, t, 32);
      uint2 u0 = m2[(size_t)s0*32 + lane];
      float2 q0 = bfpair(u0.x), q1 = bfpair(u0.y);
      a0 += w0*q0.x; a1 += w0*q0.y; a2 += w0*q1.x; a3 += w0*q1.y;
    }
  }

  float4 bv = ((const float4*)bias)[lane];
  a0 += bv.x; a1 += bv.y; a2 += bv.z; a3 += bv.w;
  float n2 = a0*a0 + a1*a1 + a2*a2 + a3*a3;
  #pragma unroll
  for (int o = 16; o > 0; o >>= 1) n2 += __shfl_xor(n2, o);
  float sc = (n2/(1.f+n2)) * rsqrtf(n2 + 1e-12f);
  float h0 = a0*sc, h1 = a1*sc, h2 = a2*sc, h3 = a3*sc;
  ((uint2*)(h + (size_t)node*128))[lane] = make_uint2(packbf(h0,h1), packbf(h2,h3));
  float4 tv = ((const float4*)tar)[lane];
  float at = h0*tv.x + h1*tv.y + h2*tv.z + h3*tv.w;
  #pragma unroll
  for (int o = 16; o > 0; o >>= 1) at += __shfl_xor(at, o);
  if (lane == 0) attn[node] = at;
}

// ---------------- per-graph readout (wsum / mean / max), accumulated ----------------
__global__ __launch_bounds__(1024) void readout(const unsigned short* __restrict__ h,
                                                const float* __restrict__ attn,
                                                const int* __restrict__ gstart,
                                                float* __restrict__ grep){
  int g = blockIdx.x;
  int t   = threadIdx.x & 63;
  int grp = threadIdx.x >> 6;
  int a = gstart[g], b = gstart[g+1];
  float wsx = 0.f, wsy = 0.f, smx_ = 0.f, smy_ = 0.f;
  float mxx = -INFINITY, mxy = -INFINITY;
  for (int n = a + grp; n < b; n += 16){
    unsigned u = ((const unsigned*)(h + (size_t)n*128))[t];
    float2 v = bfpair(u);
    float at = attn[n];
    wsx += at*v.x; wsy += at*v.y;
    smx_ += v.x;  smy_ += v.y;
    mxx = fmaxf(mxx, v.x); mxy = fmaxf(mxy, v.y);
  }
  __shared__ float2 sws[16][64], ssm[16][64], smx[16][64];
  sws[grp][t] = make_float2(wsx, wsy);
  ssm[grp][t] = make_float2(smx_, smy_);
  smx[grp][t] = make_float2(mxx, mxy);
  __syncthreads();
  if (grp == 0){
    #pragma unroll
    for (int j = 1; j < 16; ++j){
      float2 ow = sws[j][t], os = ssm[j][t], om = smx[j][t];
      wsx += ow.x; wsy += ow.y;
      smx_ += os.x; smy_ += os.y;
      mxx = fmaxf(mxx, om.x); mxy = fmaxf(mxy, om.y);
    }
    int cnt = b - a;
    float inv = 1.f / fmaxf((float)cnt, 1.f);
    if (cnt == 0){ mxx = 0.f; mxy = 0.f; }
    grep[(size_t)g*384 + t*2]           += wsx;
    grep[(size_t)g*384 + t*2 + 1]       += wsy;
    grep[(size_t)g*384 + 128 + t*2]     += smx_*inv;
    grep[(size_t)g*384 + 128 + t*2 + 1] += smy_*inv;
    grep[(size_t)g*384 + 256 + t*2]     += mxx;
    grep[(size_t)g*384 + 256 + t*2 + 1] += mxy;
  }
}

// ---------------- classifier head + log_softmax ----------------
__global__ __launch_bounds__(128) void classify(const float* __restrict__ grep,
                                                const float* __restrict__ w1, const float* __restrict__ b1,
                                                const float* __restrict__ w2, const float* __restrict__ b2,
                                                float* __restrict__ out){
  int g = blockIdx.x, t = threadIdx.x;
  __shared__ float gr[384];
  for (int i = t; i < 384; i += 128) gr[i] = grep[(size_t)g*384 + i];
  __syncthreads();
  float z = b1[t];
  for (int k = 0; k < 384; ++k) z += gr[k]*w1[k*128 + t];
  z = fmaxf(z, 0.f);
  float c0 = z*w2[t*2 + 0], c1 = z*w2[t*2 + 1];
  #pragma unroll
  for (int o = 32; o > 0; o >>= 1){ c0 += __shfl_xor(c0, o); c1 += __shfl_xor(c1, o); }
  __shared__ float r0s[2], r1s[2];
  if ((t & 63) == 0){ r0s[t>>6] = c0; r1s[t>>6] = c1; }
  __syncthreads();
  if (t == 0){
    float z0 = r0s[0] + r0s[1] + b2[0];
    float z1 = r1s[0] + r1s[1] + b2[1];
    float mm = fmaxf(z0, z1);
    float lse = mm + logf(expf(z0-mm) + expf(z1-mm));
    out[g*2 + 0] = z0 - lse;
    out[g*2 + 1] = z1 - lse;
  }
}

extern "C" void kernel_launch(void* const* d_in, const int* in_sizes, int n_in,
                              void* d_out, int out_size, void* d_ws, size_t ws_size,
                              hipStream_t stream) {
  const float* x     = (const float*)d_in[0];
  const int*   ei    = (const int*)d_in[1];
  const int*   batch = (const int*)d_in[2];
  const float* gamma = (const float*)d_in[3];
  const float* beta  = (const float*)d_in[4];
  const float* W0    = (const float*)d_in[5];
  const float* b0    = (const float*)d_in[6];
  const float* W1    = (const float*)d_in[7];
  const float* b1    = (const float*)d_in[8];
  const float* W2    = (const float*)d_in[9];
  const float* b2    = (const float*)d_in[10];
  const float* tar   = (const float*)d_in[11];
  const float* l1w   = (const float*)d_in[12];
  const float* l1b   = (const float*)d_in[13];
  const float* l2w   = (const float*)d_in[14];
  const float* l2b   = (const float*)d_in[15];
  float* out = (float*)d_out;

  int N = in_sizes[0] / 128;
  int E = in_sizes[1] / 2;
  int G = out_size / 2;
  const int* srcp = ei;
  const int* dstp = ei + E;

  char* wsb = (char*)d_ws;
  size_t off = 0;
  auto alloc = [&](size_t bytes)->char*{
    char* p = wsb + off; off += (bytes + 255) & ~(size_t)255; return p;
  };
  unsigned short* h = (unsigned short*)alloc((size_t)N*128*2);
  unsigned short* m = (unsigned short*)alloc((size_t)N*128*2);
  float* attn    = (float*)alloc((size_t)N*4);
  float* dinv    = (float*)alloc((size_t)N*4);
  int*   indeg   = (int*)  alloc((size_t)N*4);
  int*   rowst   = (int*)  alloc((size_t)(N+1)*4);
  int*   cursor  = (int*)  alloc((size_t)N*4);
  uint2* csre    = (uint2*)alloc((size_t)E*8);
  int*   gstart  = (int*)  alloc((size_t)(G+1)*4);
  float* grep    = (float*)alloc((size_t)G*384*4);
  float* stats   = (float*)alloc(2*128*4);
  float* part    = (float*)alloc((size_t)BN_BLOCKS*256*4);
  unsigned short* Wh = (unsigned short*)alloc(3*16384*2);
  unsigned short* Wl = (unsigned short*)alloc(3*16384*2);
  int*   bsum    = (int*)  alloc(256*4);
  (void)ws_size;

  float* scale  = stats;
  float* shift  = stats + 128;

  hipMemsetAsync(indeg, 0, (size_t)N*4, stream);
  hipMemsetAsync(grep, 0, (size_t)G*384*4, stream);

  // --- CSR build first (absorbs first-kernel cold-start) ---
  int nb = (N + SCAN_CHUNK - 1) / SCAN_CHUNK;
  count_deg<<<(E+255)/256, 256, 0, stream>>>(dstp, indeg, E);
  dinv_k<<<(N+255)/256, 256, 0, stream>>>(indeg, dinv, N);
  scan_part<<<nb, 256, 0, stream>>>(indeg, bsum, N);
  scan_bsum<<<1, 256, 0, stream>>>(bsum, nb);
  scan_fill<<<nb, 256, 0, stream>>>(indeg, bsum, rowst, cursor, N);
  fill_csr<<<(E+255)/256, 256, 0, stream>>>(srcp, dstp, dinv, cursor, csre, E);
  gbounds<<<(G+1+255)/256, 256, 0, stream>>>(batch, gstart, N, G);
  prep_w<<<(3*16384+255)/256, 256, 0, stream>>>(W0, W1, W2, Wh, Wl);

  // --- BatchNorm stats: atomic-free two-stage ---
  bn_part<<<BN_BLOCKS, 256, 0, stream>>>(x, part, N*32);
  bn_reduce<<<1, 256, 0, stream>>>(part, gamma, beta, scale, shift, N);

  const float* bs[3] = {b0, b1, b2};
  for (int l = 0; l < 3; ++l){
    if (l == 0)
      gemm_mfma<0><<<(N+63)/64, 256, 0, stream>>>(x, nullptr, Wh, Wl, scale, shift, m, N);
    else
      gemm_mfma<1><<<(N+63)/64, 256, 0, stream>>>(nullptr, h, Wh + l*16384, Wl + l*16384, scale, shift, m, N);
    gather_squash<<<(N+7)/8, 256, 0, stream>>>(m, rowst, csre, dinv, bs[l], tar + l*128, h, attn, N);
    readout<<<G, 1024, 0, stream>>>(h, attn, gstart, grep);
  }
  classify<<<G, 128, 0, stream>>>(grep, l1w, l1b, l2w, l2b, out);
}

// Round 10
// 301.620 us; speedup vs baseline: 1.7315x; 1.0712x over previous
//
#include <hip/hip_runtime.h>
#include <hip/hip_bf16.h>
#include <math.h>

#define BN_EPS 1e-5f
#define SCAN_CHUNK 1024
#define BN_BLOCKS 512

typedef __attribute__((ext_vector_type(8)))  short short8v;
typedef __attribute__((ext_vector_type(16))) float f32x16;

__device__ __forceinline__ unsigned short f2bf(float f){
  union { float f; unsigned u; } v; v.f = f;
  unsigned r = v.u + 0x7FFFu + ((v.u >> 16) & 1u);
  return (unsigned short)(r >> 16);
}
__device__ __forceinline__ float bf2f(unsigned short b){
  union { unsigned u; float f; } v; v.u = ((unsigned)b) << 16;
  return v.f;
}
__device__ __forceinline__ float2 bfpair(unsigned u){
  union { unsigned u; float f; } lo, hi;
  lo.u = u << 16;
  hi.u = u & 0xFFFF0000u;
  return make_float2(lo.f, hi.f);
}
__device__ __forceinline__ unsigned packbf(float a, float b){
  return (unsigned)f2bf(a) | ((unsigned)f2bf(b) << 16);
}

// ---------------- BatchNorm stats (two-stage, no atomics) ----------------
__global__ __launch_bounds__(256) void bn_part(const float* __restrict__ x,
                                               float* __restrict__ part, int total4){
  const float4* x4 = (const float4*)x;
  int stride = gridDim.x * blockDim.x;
  float4 s = make_float4(0.f,0.f,0.f,0.f);
  float4 q = make_float4(0.f,0.f,0.f,0.f);
  for (int idx = blockIdx.x*blockDim.x + threadIdx.x; idx < total4; idx += stride){
    float4 v = x4[idx];
    s.x += v.x; s.y += v.y; s.z += v.z; s.w += v.w;
    q.x += v.x*v.x; q.y += v.y*v.y; q.z += v.z*v.z; q.w += v.w*v.w;
  }
  __shared__ float4 shs[256], shq[256];
  shs[threadIdx.x] = s; shq[threadIdx.x] = q;
  __syncthreads();
  if (threadIdx.x < 32){
    int c4 = threadIdx.x;
    float4 ts = shs[c4], tq = shq[c4];
    #pragma unroll
    for (int j = 1; j < 8; ++j){
      float4 os = shs[c4 + j*32], oq = shq[c4 + j*32];
      ts.x += os.x; ts.y += os.y; ts.z += os.z; ts.w += os.w;
      tq.x += oq.x; tq.y += oq.y; tq.z += oq.z; tq.w += oq.w;
    }
    float* pb = part + (size_t)blockIdx.x * 256;
    *(float4*)(pb + c4*4)       = ts;
    *(float4*)(pb + 128 + c4*4) = tq;
  }
}

__global__ __launch_bounds__(256) void bn_reduce(const float* __restrict__ part,
                                                 const float* __restrict__ gamma,
                                                 const float* __restrict__ beta,
                                                 float* __restrict__ scale,
                                                 float* __restrict__ shift, int N){
  int t = threadIdx.x;
  float a0=0.f,a1=0.f,a2=0.f,a3=0.f,a4=0.f,a5=0.f,a6=0.f,a7=0.f;
  for (int b = 0; b < BN_BLOCKS; b += 8){
    a0 += part[(size_t)(b+0)*256 + t];
    a1 += part[(size_t)(b+1)*256 + t];
    a2 += part[(size_t)(b+2)*256 + t];
    a3 += part[(size_t)(b+3)*256 + t];
    a4 += part[(size_t)(b+4)*256 + t];
    a5 += part[(size_t)(b+5)*256 + t];
    a6 += part[(size_t)(b+6)*256 + t];
    a7 += part[(size_t)(b+7)*256 + t];
  }
  float acc = ((a0+a1)+(a2+a3)) + ((a4+a5)+(a6+a7));
  __shared__ float sh[256];
  sh[t] = acc;
  __syncthreads();
  if (t < 128){
    float mu  = sh[t] / (float)N;
    float var = sh[t+128] / (float)N - mu*mu;
    float sc  = gamma[t] * rsqrtf(var + BN_EPS);
    scale[t] = sc;
    shift[t] = beta[t] - mu*sc;
  }
}

// ---------------- CSR build ----------------
__global__ void count_deg(const int* __restrict__ dst, int* __restrict__ indeg, int E){
  int e = blockIdx.x*blockDim.x + threadIdx.x;
  if (e < E) atomicAdd(&indeg[dst[e]], 1);
}

__global__ void dinv_k(const int* __restrict__ indeg, float* __restrict__ dinv, int N){
  int v = blockIdx.x*blockDim.x + threadIdx.x;
  if (v < N) dinv[v] = rsqrtf((float)indeg[v] + 1.0f);
}

__global__ __launch_bounds__(256) void scan_part(const int* __restrict__ indeg,
                                                 int* __restrict__ bsum, int N){
  __shared__ int sh[256];
  int base = blockIdx.x * SCAN_CHUNK;
  int s = 0;
  for (int i = threadIdx.x; i < SCAN_CHUNK; i += 256){
    int idx = base + i;
    if (idx < N) s += indeg[idx];
  }
  sh[threadIdx.x] = s; __syncthreads();
  for (int d = 128; d > 0; d >>= 1){
    if (threadIdx.x < d) sh[threadIdx.x] += sh[threadIdx.x + d];
    __syncthreads();
  }
  if (threadIdx.x == 0) bsum[blockIdx.x] = sh[0];
}

__global__ __launch_bounds__(256) void scan_bsum(int* __restrict__ bsum, int nb){
  __shared__ int sh[256];
  int tid = threadIdx.x;
  int v = (tid < nb) ? bsum[tid] : 0;
  sh[tid] = v; __syncthreads();
  for (int d = 1; d < 256; d <<= 1){
    int t = (tid >= d) ? sh[tid-d] : 0;
    __syncthreads();
    sh[tid] += t;
    __syncthreads();
  }
  if (tid < nb) bsum[tid] = sh[tid] - v;
}

__global__ __launch_bounds__(256) void scan_fill(const int* __restrict__ indeg,
                                                 const int* __restrict__ bsum,
                                                 int* __restrict__ rowstart,
                                                 int* __restrict__ cursor, int N){
  __shared__ int sh[256];
  int base = blockIdx.x * SCAN_CHUNK;
  int tid = threadIdx.x;
  int i0 = base + tid*4;
  int v[4]; int s = 0;
  #pragma unroll
  for (int j=0;j<4;j++){
    int idx = i0 + j;
    v[j] = (idx < N) ? indeg[idx] : 0;
    s += v[j];
  }
  sh[tid] = s; __syncthreads();
  for (int d = 1; d < 256; d <<= 1){
    int t = (tid >= d) ? sh[tid-d] : 0;
    __syncthreads();
    sh[tid] += t;
    __syncthreads();
  }
  int off = bsum[blockIdx.x] + sh[tid] - s;
  #pragma unroll
  for (int j=0;j<4;j++){
    int idx = i0 + j;
    if (idx < N){ rowstart[idx] = off; cursor[idx] = off; }
    off += v[j];
  }
  if (blockIdx.x == gridDim.x - 1 && tid == 255) rowstart[N] = off;
}

// packed edge record: .x = src index, .y = norm (float bits)
__global__ void fill_csr(const int* __restrict__ src, const int* __restrict__ dst,
                         const float* __restrict__ dinv, int* __restrict__ cursor,
                         uint2* __restrict__ csre, int E){
  int e = blockIdx.x*blockDim.x + threadIdx.x;
  if (e < E){
    int s = src[e], d = dst[e];
    int pos = atomicAdd(&cursor[d], 1);
    union { float f; unsigned u; } w; w.f = dinv[s]*dinv[d];
    csre[pos] = make_uint2((unsigned)s, w.u);
  }
}

__global__ void gbounds(const int* __restrict__ batch, int* __restrict__ gstart, int N, int G){
  int g = blockIdx.x*blockDim.x + threadIdx.x;
  if (g > G) return;
  int lo = 0, hi = N;
  while (lo < hi){ int mid = (lo+hi)>>1; if (batch[mid] < g) lo = mid+1; else hi = mid; }
  gstart[g] = lo;
}

// ---- W -> bf16 transposed Wt[l][c][k]; layer-0 gets BN scale folded in ----
__global__ void prep_w(const float* __restrict__ W0, const float* __restrict__ W1,
                       const float* __restrict__ W2, const float* __restrict__ scale,
                       unsigned short* __restrict__ Wh){
  int idx = blockIdx.x*blockDim.x + threadIdx.x;
  if (idx >= 3*16384) return;
  int l = idx >> 14, r = idx & 16383, c = r >> 7, k = r & 127;
  const float* W = (l==0) ? W0 : (l==1) ? W1 : W2;
  float v = W[k*128 + c];
  if (l == 0) v *= scale[k];
  Wh[idx] = f2bf(v);
}

// ---- layer-0 bias': b0 + shift @ W0 (BN shift folded) ----
__global__ __launch_bounds__(128) void prep_bias0(const float* __restrict__ b0,
                                                  const float* __restrict__ shift,
                                                  const float* __restrict__ W0,
                                                  float* __restrict__ bias0p){
  int j = threadIdx.x;
  __shared__ float sh[128];
  sh[j] = shift[j];
  __syncthreads();
  float s = b0[j];
  for (int c = 0; c < 128; ++c) s += sh[c] * W0[c*128 + j];
  bias0p[j] = s;
}

// ---------------- lean MFMA GEMM: C[N,128] (bf16) = A @ W_hi ----------------
// 512 thr = 8 waves; wave w owns one 32x32 tile: rows 32*(w&1), cols 32*(w>>1).
// bhf[8] = 32 VGPR, acc 16 -> no spill. LDS 16 KB (A only, swizzled).
// CVT=1: A from fp32 (layer 0, BN pre-folded into W/bias). CVT=0: A bf16 copy.
template<int CVT>
__global__ __launch_bounds__(512) void gemm_mfma(
    const float* __restrict__ A32, const unsigned short* __restrict__ A16,
    const unsigned short* __restrict__ Bh, unsigned short* __restrict__ C, int N){
  __shared__ unsigned short Ah[64*128];
  int tid = threadIdx.x;
  int r0 = blockIdx.x * 64;
  int w = tid >> 6, lane = tid & 63;
  int rt = w & 1;
  int ct = (w >> 1) * 32;
  int lrow = 32*rt + (lane & 31);
  int khalf = lane >> 5;
  int c0 = ct + (lane & 31);
  const unsigned short* bh0 = Bh + (size_t)c0*128 + khalf*8;

  // preload this wave's B fragments (32 VGPR), in flight under A staging
  short8v bhf[8];
  #pragma unroll
  for (int s = 0; s < 8; ++s) bhf[s] = *(const short8v*)(bh0 + s*16);

  if (CVT){
    #pragma unroll
    for (int it = 0; it < 4; ++it){
      int idx = tid + it*512;          // 0..2047 float4
      int row = idx >> 5;
      int c4  = idx & 31;
      int r = r0 + row;
      float4 av = (r < N) ? *(const float4*)(A32 + (size_t)r*128 + c4*4)
                          : make_float4(0.f,0.f,0.f,0.f);
      int byte0 = (c4*8) ^ ((row & 15) << 4);
      uint2 p = make_uint2(packbf(av.x, av.y), packbf(av.z, av.w));
      *(uint2*)((char*)Ah + row*256 + byte0) = p;
    }
  } else {
    #pragma unroll
    for (int it = 0; it < 2; ++it){
      int idx = tid + it*512;          // 0..1023 uint4
      int row = idx >> 4;
      int c8  = idx & 15;
      int r = r0 + row;
      uint4 v = (r < N) ? *(const uint4*)(A16 + (size_t)r*128 + c8*8)
                        : make_uint4(0,0,0,0);
      int byte0 = (c8*16) ^ ((row & 15) << 4);
      *(uint4*)((char*)Ah + row*256 + byte0) = v;
    }
  }
  __syncthreads();

  f32x16 acc = {};
  const char* AhB = (const char*)Ah + lrow*256;
  int sw = (lrow & 15) << 4;
  #pragma unroll
  for (int s = 0; s < 8; ++s){
    int abyte = (s*32 + khalf*16) ^ sw;
    short8v a = *(const short8v*)(AhB + abyte);
    acc = __builtin_amdgcn_mfma_f32_32x32x16_bf16(a, bhf[s], acc, 0, 0, 0);
  }

  #pragma unroll
  for (int r = 0; r < 16; ++r){
    int row = r0 + 32*rt + (r & 3) + 8*(r >> 2) + 4*khalf;
    if (row < N) C[(size_t)row*128 + c0] = f2bf(acc[r]);
  }
}

// ---------------- fused aggregation + bias + squash + attention ----------------
__global__ __launch_bounds__(256) void gather_squash(
    const unsigned short* __restrict__ m, const int* __restrict__ rowstart,
    const uint2* __restrict__ csre, const float* __restrict__ dinv,
    const float* __restrict__ bias, const float* __restrict__ tar,
    unsigned short* __restrict__ h, float* __restrict__ attn, int N){
  int node = blockIdx.x*8 + (threadIdx.x >> 5);
  if (node >= N) return;
  int lane = threadIdx.x & 31;
  const uint2* m2 = (const uint2*)m;
  float dv = dinv[node];
  float sn = dv*dv;
  uint2 sv = m2[(size_t)node*32 + lane];
  float2 p0 = bfpair(sv.x), p1 = bfpair(sv.y);
  float a0 = p0.x*sn, a1 = p0.y*sn, a2 = p1.x*sn, a3 = p1.y*sn;
  int j0 = rowstart[node], j1 = rowstart[node+1];

  for (int base = j0; base < j1; base += 32){
    int cnt = j1 - base; if (cnt > 32) cnt = 32;
    int sidx = 0; float swt = 0.f;
    if (lane < cnt){
      uint2 ce = csre[base + lane];
      sidx = (int)ce.x;
      union { unsigned u; float f; } wv; wv.u = ce.y;
      swt = wv.f;
    }
    int t = 0;
    for (; t + 4 <= cnt; t += 4){
      int s0 = __shfl(sidx, t, 32),   s1 = __shfl(sidx, t+1, 32);
      int s2 = __shfl(sidx, t+2, 32), s3 = __shfl(sidx, t+3, 32);
      float w0 = __shfl(swt, t, 32),   w1 = __shfl(swt, t+1, 32);
      float w2 = __shfl(swt, t+2, 32), w3 = __shfl(swt, t+3, 32);
      uint2 u0 = m2[(size_t)s0*32 + lane];
      uint2 u1 = m2[(size_t)s1*32 + lane];
      uint2 u2 = m2[(size_t)s2*32 + lane];
      uint2 u3 = m2[(size_t)s3*32 + lane];
      float2 q0, q1;
      q0 = bfpair(u0.x); q1 = bfpair(u0.y);
      a0 += w0*q0.x; a1 += w0*q0.y; a2 += w0*q1.x; a3 += w0*q1.y;
      q0 = bfpair(u1.x); q1 = bfpair(u1.y);
      a0 += w1*q0.x; a1 += w1*q0.y; a2 += w1*q1.x; a3 += w1*q1.y;
      q0 = bfpair(u2.x); q1 = bfpair(u2.y);
      a0 += w2*q0.x; a1 += w2*q0.y; a2 += w2*q1.x; a3 += w2*q1.y;
      q0 = bfpair(u3.x); q1 = bfpair(u3.y);
      a0 += w3*q0.x; a1 += w3*q0.y; a2 += w3*q1.x; a3 += w3*q1.y;
    }
    if (cnt - t >= 2){
      int s0 = __shfl(sidx, t, 32), s1 = __shfl(sidx, t+1, 32);
      float w0 = __shfl(swt, t, 32), w1 = __shfl(swt, t+1, 32);
      uint2 u0 = m2[(size_t)s0*32 + lane];
      uint2 u1 = m2[(size_t)s1*32 + lane];
      float2 q0 = bfpair(u0.x), q1 = bfpair(u0.y);
      a0 += w0*q0.x; a1 += w0*q0.y; a2 += w0*q1.x; a3 += w0*q1.y;
      q0 = bfpair(u1.x); q1 = bfpair(u1.y);
      a0 += w1*q0.x; a1 += w1*q0.y; a2 += w1*q1.x; a3 += w1*q1.y;
      t += 2;
    }
    if (t < cnt){
      int s0 = __shfl(sidx, t, 32);
      float w0 = __shfl(swt, t, 32);
      uint2 u0 = m2[(size_t)s0*32 + lane];
      float2 q0 = bfpair(u0.x), q1 = bfpair(u0.y);
      a0 += w0*q0.x; a1 += w0*q0.y; a2 += w0*q1.x; a3 += w0*q1.y;
    }
  }

  float4 bv = ((const float4*)bias)[lane];
  a0 += bv.x; a1 += bv.y; a2 += bv.z; a3 += bv.w;
  float n2 = a0*a0 + a1*a1 + a2*a2 + a3*a3;
  #pragma unroll
  for (int o = 16; o > 0; o >>= 1) n2 += __shfl_xor(n2, o);
  float sc = (n2/(1.f+n2)) * rsqrtf(n2 + 1e-12f);
  float h0 = a0*sc, h1 = a1*sc, h2 = a2*sc, h3 = a3*sc;
  ((uint2*)(h + (size_t)node*128))[lane] = make_uint2(packbf(h0,h1), packbf(h2,h3));
  float4 tv = ((const float4*)tar)[lane];
  float at = h0*tv.x + h1*tv.y + h2*tv.z + h3*tv.w;
  #pragma unroll
  for (int o = 16; o > 0; o >>= 1) at += __shfl_xor(at, o);
  if (lane == 0) attn[node] = at;
}

// ---------------- per-graph readout (wsum / mean / max), accumulated ----------------
__global__ __launch_bounds__(1024) void readout(const unsigned short* __restrict__ h,
                                                const float* __restrict__ attn,
                                                const int* __restrict__ gstart,
                                                float* __restrict__ grep){
  int g = blockIdx.x;
  int t   = threadIdx.x & 63;
  int grp = threadIdx.x >> 6;
  int a = gstart[g], b = gstart[g+1];
  float wsx = 0.f, wsy = 0.f, smx_ = 0.f, smy_ = 0.f;
  float mxx = -INFINITY, mxy = -INFINITY;
  for (int n = a + grp; n < b; n += 16){
    unsigned u = ((const unsigned*)(h + (size_t)n*128))[t];
    float2 v = bfpair(u);
    float at = attn[n];
    wsx += at*v.x; wsy += at*v.y;
    smx_ += v.x;  smy_ += v.y;
    mxx = fmaxf(mxx, v.x); mxy = fmaxf(mxy, v.y);
  }
  __shared__ float2 sws[16][64], ssm[16][64], smx[16][64];
  sws[grp][t] = make_float2(wsx, wsy);
  ssm[grp][t] = make_float2(smx_, smy_);
  smx[grp][t] = make_float2(mxx, mxy);
  __syncthreads();
  if (grp == 0){
    #pragma unroll
    for (int j = 1; j < 16; ++j){
      float2 ow = sws[j][t], os = ssm[j][t], om = smx[j][t];
      wsx += ow.x; wsy += ow.y;
      smx_ += os.x; smy_ += os.y;
      mxx = fmaxf(mxx, om.x); mxy = fmaxf(mxy, om.y);
    }
    int cnt = b - a;
    float inv = 1.f / fmaxf((float)cnt, 1.f);
    if (cnt == 0){ mxx = 0.f; mxy = 0.f; }
    grep[(size_t)g*384 + t*2]           += wsx;
    grep[(size_t)g*384 + t*2 + 1]       += wsy;
    grep[(size_t)g*384 + 128 + t*2]     += smx_*inv;
    grep[(size_t)g*384 + 128 + t*2 + 1] += smy_*inv;
    grep[(size_t)g*384 + 256 + t*2]     += mxx;
    grep[(size_t)g*384 + 256 + t*2 + 1] += mxy;
  }
}

// ---------------- classifier head + log_softmax ----------------
__global__ __launch_bounds__(128) void classify(const float* __restrict__ grep,
                                                const float* __restrict__ w1, const float* __restrict__ b1,
                                                const float* __restrict__ w2, const float* __restrict__ b2,
                                                float* __restrict__ out){
  int g = blockIdx.x, t = threadIdx.x;
  __shared__ float gr[384];
  for (int i = t; i < 384; i += 128) gr[i] = grep[(size_t)g*384 + i];
  __syncthreads();
  float z = b1[t];
  for (int k = 0; k < 384; ++k) z += gr[k]*w1[k*128 + t];
  z = fmaxf(z, 0.f);
  float c0 = z*w2[t*2 + 0], c1 = z*w2[t*2 + 1];
  #pragma unroll
  for (int o = 32; o > 0; o >>= 1){ c0 += __shfl_xor(c0, o); c1 += __shfl_xor(c1, o); }
  __shared__ float r0s[2], r1s[2];
  if ((t & 63) == 0){ r0s[t>>6] = c0; r1s[t>>6] = c1; }
  __syncthreads();
  if (t == 0){
    float z0 = r0s[0] + r0s[1] + b2[0];
    float z1 = r1s[0] + r1s[1] + b2[1];
    float mm = fmaxf(z0, z1);
    float lse = mm + logf(expf(z0-mm) + expf(z1-mm));
    out[g*2 + 0] = z0 - lse;
    out[g*2 + 1] = z1 - lse;
  }
}

extern "C" void kernel_launch(void* const* d_in, const int* in_sizes, int n_in,
                              void* d_out, int out_size, void* d_ws, size_t ws_size,
                              hipStream_t stream) {
  const float* x     = (const float*)d_in[0];
  const int*   ei    = (const int*)d_in[1];
  const int*   batch = (const int*)d_in[2];
  const float* gamma = (const float*)d_in[3];
  const float* beta  = (const float*)d_in[4];
  const float* W0    = (const float*)d_in[5];
  const float* b0    = (const float*)d_in[6];
  const float* W1    = (const float*)d_in[7];
  const float* b1    = (const float*)d_in[8];
  const float* W2    = (const float*)d_in[9];
  const float* b2    = (const float*)d_in[10];
  const float* tar   = (const float*)d_in[11];
  const float* l1w   = (const float*)d_in[12];
  const float* l1b   = (const float*)d_in[13];
  const float* l2w   = (const float*)d_in[14];
  const float* l2b   = (const float*)d_in[15];
  float* out = (float*)d_out;

  int N = in_sizes[0] / 128;
  int E = in_sizes[1] / 2;
  int G = out_size / 2;
  const int* srcp = ei;
  const int* dstp = ei + E;

  char* wsb = (char*)d_ws;
  size_t off = 0;
  auto alloc = [&](size_t bytes)->char*{
    char* p = wsb + off; off += (bytes + 255) & ~(size_t)255; return p;
  };
  unsigned short* h = (unsigned short*)alloc((size_t)N*128*2);
  unsigned short* m = (unsigned short*)alloc((size_t)N*128*2);
  float* attn    = (float*)alloc((size_t)N*4);
  float* dinv    = (float*)alloc((size_t)N*4);
  int*   indeg   = (int*)  alloc((size_t)N*4);
  int*   rowst   = (int*)  alloc((size_t)(N+1)*4);
  int*   cursor  = (int*)  alloc((size_t)N*4);
  uint2* csre    = (uint2*)alloc((size_t)E*8);
  int*   gstart  = (int*)  alloc((size_t)(G+1)*4);
  float* grep    = (float*)alloc((size_t)G*384*4);
  float* stats   = (float*)alloc(2*128*4);
  float* bias0p  = (float*)alloc(128*4);
  float* part    = (float*)alloc((size_t)BN_BLOCKS*256*4);
  unsigned short* Wh = (unsigned short*)alloc(3*16384*2);
  int*   bsum    = (int*)  alloc(256*4);
  (void)ws_size;

  float* scale  = stats;
  float* shift  = stats + 128;

  hipMemsetAsync(indeg, 0, (size_t)N*4, stream);
  hipMemsetAsync(grep, 0, (size_t)G*384*4, stream);

  // --- CSR build first (absorbs first-kernel cold-start) ---
  int nb = (N + SCAN_CHUNK - 1) / SCAN_CHUNK;
  count_deg<<<(E+255)/256, 256, 0, stream>>>(dstp, indeg, E);
  dinv_k<<<(N+255)/256, 256, 0, stream>>>(indeg, dinv, N);
  scan_part<<<nb, 256, 0, stream>>>(indeg, bsum, N);
  scan_bsum<<<1, 256, 0, stream>>>(bsum, nb);
  scan_fill<<<nb, 256, 0, stream>>>(indeg, bsum, rowst, cursor, N);
  fill_csr<<<(E+255)/256, 256, 0, stream>>>(srcp, dstp, dinv, cursor, csre, E);
  gbounds<<<(G+1+255)/256, 256, 0, stream>>>(batch, gstart, N, G);

  // --- BatchNorm stats, then fold into W0'/bias0' ---
  bn_part<<<BN_BLOCKS, 256, 0, stream>>>(x, part, N*32);
  bn_reduce<<<1, 256, 0, stream>>>(part, gamma, beta, scale, shift, N);
  prep_w<<<(3*16384+255)/256, 256, 0, stream>>>(W0, W1, W2, scale, Wh);
  prep_bias0<<<1, 128, 0, stream>>>(b0, shift, W0, bias0p);

  const float* bs[3] = {bias0p, b1, b2};
  int nb64 = (N + 63) / 64;
  for (int l = 0; l < 3; ++l){
    if (l == 0)
      gemm_mfma<1><<<nb64, 512, 0, stream>>>(x, nullptr, Wh, m, N);
    else
      gemm_mfma<0><<<nb64, 512, 0, stream>>>(nullptr, h, Wh + l*16384, m, N);
    gather_squash<<<(N+7)/8, 256, 0, stream>>>(m, rowst, csre, dinv, bs[l], tar + l*128, h, attn, N);
    readout<<<G, 1024, 0, stream>>>(h, attn, gstart, grep);
  }
  classify<<<G, 128, 0, stream>>>(grep, l1w, l1b, l2w, l2b, out);
}